// Round 2
// baseline (2017.352 us; speedup 1.0000x reference)
//
#include <hip/hip_runtime.h>
#include <hip/hip_bf16.h>
#include <math.h>

// ---------------- constants ----------------
#define Bq     4
#define LSEQ   515          // 3 meta + 512 data tokens
#define NMETA  3
#define NPATCH 512
#define Dm     384
#define NHEADS 6
#define HDh    64
#define NDEPTH 12
#define LPAD   544          // 515 padded to multiple of 32

typedef unsigned short u16;
typedef short bf16x8 __attribute__((ext_vector_type(8)));
typedef float f32x4  __attribute__((ext_vector_type(4)));

enum { EPI_F32 = 0, EPI_BF16 = 1, EPI_GELU = 2, EPI_RES = 3 };

__device__ inline u16 f2bf(float x) {
    __hip_bfloat16 h = __float2bfloat16(x);
    return *reinterpret_cast<u16*>(&h);
}

// ---------------- weight transpose + cast: W (R x C) f32 -> WT (C x R) bf16, per layer z ----
__global__ __launch_bounds__(256)
void k_transpose(const float* __restrict__ W, u16* __restrict__ WT, int R, int C) {
    __shared__ float tile[32][33];
    int z = blockIdx.z;
    const float* Wz = W + (long)z * R * C;
    u16* Tz = WT + (long)z * R * C;
    int c0 = blockIdx.x * 32, r0 = blockIdx.y * 32;
    int tx = threadIdx.x & 31, ty = threadIdx.x >> 5;     // 32 x 8
    for (int rr = ty; rr < 32; rr += 8)
        tile[rr][tx] = Wz[(long)(r0 + rr) * C + c0 + tx];
    __syncthreads();
    for (int rr = ty; rr < 32; rr += 8)
        Tz[(long)(c0 + rr) * R + r0 + tx] = f2bf(tile[tx][rr]);
}

// ---------------- patch embed (fp32): one block per patch --------------------
__global__ __launch_bounds__(256)
void k_patch(const float* __restrict__ x, const float* __restrict__ pw,
             const float* __restrict__ pb, const int* __restrict__ chan,
             const float* __restrict__ ctab, float* __restrict__ tmp) {
    __shared__ float px[256];
    int m = blockIdx.x;               // 0..2047  (b*512 + n)
    int b = m >> 9, n = m & 511;
    int i = n >> 6, j = n & 63;       // patch grid 8 x 64
    int t = threadIdx.x;
    int pr = t >> 4, pc = t & 15;
    px[t] = x[(long)b * 131072 + (i * 16 + pr) * 1024 + j * 16 + pc];
    __syncthreads();
    int ch = chan[m];
    for (int d = t; d < Dm; d += 256) {
        const float* wr_ = pw + (long)d * 256;
        float a = 0.f;
        #pragma unroll 8
        for (int k = 0; k < 256; k++) a += px[k] * wr_[k];
        tmp[(long)m * Dm + d] = a + pb[d] + ctab[(long)ch * Dm + d];
    }
}

// ---------------- stable argsort of noise rows (512) via bitonic w/ index tie-break ----
__global__ __launch_bounds__(512)
void k_argsort(const float* __restrict__ noise, int* __restrict__ ids) {
    __shared__ float v[512];
    __shared__ int   ix[512];
    int b = blockIdx.x, t = threadIdx.x;
    v[t] = noise[b * 512 + t]; ix[t] = t;
    __syncthreads();
    for (int k = 2; k <= 512; k <<= 1)
        for (int j = k >> 1; j > 0; j >>= 1) {
            int p = t ^ j;
            if (p > t) {
                bool up = (t & k) == 0;
                float va = v[t], vb = v[p]; int ia = ix[t], ib = ix[p];
                bool sw = (va > vb) || (va == vb && ia > ib);
                if (sw == up) { v[t] = vb; v[p] = va; ix[t] = ib; ix[p] = ia; }
            }
            __syncthreads();
        }
    ids[b * 512 + t] = ix[t];
}

// ---------------- gather data tokens into xt rows [3..514] -------------------
__global__ void k_gather(const float* __restrict__ tmp, const int* __restrict__ ids,
                         float* __restrict__ xt) {
    long t = (long)blockIdx.x * 256 + threadIdx.x;
    if (t >= (long)Bq * NPATCH * Dm) return;
    int d = t % Dm; long r = t / Dm;
    int j = r % NPATCH, b = r / NPATCH;
    int src = ids[b * NPATCH + j];
    xt[((long)b * LSEQ + NMETA + j) * Dm + d] = tmp[((long)b * NPATCH + src) * Dm + d];
}

// ---------------- meta tokens: m/s @ mean_w + mean_b -> xt rows 1,2 ----------
__global__ void k_meta(const float* __restrict__ means, const float* __restrict__ stds,
                       const float* __restrict__ mw, const float* __restrict__ mb,
                       float* __restrict__ xt) {
    int blk = blockIdx.x;             // b(4) x mi(2) x part(2)
    int part = blk & 1, mi = (blk >> 1) & 1, b = blk >> 2;
    int d = threadIdx.x;
    if (d >= 192) return;
    const float* row = (part ? stds : means) + (long)(b * 2 + mi) * 4000;
    float a = 0.f;
    for (int k = 0; k < 4000; k++) a += row[k] * mw[(long)k * 192 + d];
    a += mb[d];
    xt[((long)b * LSEQ + 1 + mi) * Dm + part * 192 + d] = a;
}

// ---------------- cls row ----------------------------------------------------
__global__ void k_cls(const float* __restrict__ cls, float* __restrict__ xt) {
    int t = blockIdx.x * 256 + threadIdx.x;
    if (t >= Bq * Dm) return;
    int b = t / Dm, d = t % Dm;
    xt[(long)b * LSEQ * Dm + d] = cls[d];
}

// ---------------- meta_patches / mask / n_meta outputs -----------------------
__global__ void k_outextra(const float* __restrict__ xt, float* __restrict__ out) {
    int t = blockIdx.x * 256 + threadIdx.x;
    const int META = Bq * NMETA * Dm;          // 4608
    const int MASKN = Bq * NPATCH;             // 2048
    if (t < META) {
        int d = t % Dm; int r = t / Dm; int b = r / NMETA, mi = r % NMETA;
        out[791040 + t] = xt[((long)b * LSEQ + mi) * Dm + d];
    } else if (t < META + MASKN) {
        out[791040 + t] = 0.0f;                // mask (len_keep == 512)
    } else if (t == META + MASKN) {
        out[791040 + t] = 3.0f;                // n_meta
    }
}

// ---------------- RoPE cos/sin table -----------------------------------------
__global__ void k_ropetab(const int* __restrict__ win, float* __restrict__ ct,
                          float* __restrict__ st) {
    int t = blockIdx.x * 256 + threadIdx.x;
    if (t >= NPATCH * 32) return;
    int p = t & 31, n = t >> 5;
    int i = n >> 6, j = n & 63;
    float step = (float)(*win) * 0.25f / 0.125f;
    float inv, ang;
    if (p < 16) { inv = powf(100.0f, -(float)p / 16.0f);        ang = (float)j * step * inv; }
    else        { inv = powf(100.0f, -(float)(p - 16) / 16.0f); ang = (float)i * inv; }
    ct[t] = cosf(ang); st[t] = sinf(ang);
}

// ---------------- layernorm: 1 wave per row, D=384 ---------------------------
template<bool OUT_BF16>
__global__ __launch_bounds__(256)
void k_ln(const float* __restrict__ X, const float* __restrict__ g,
          const float* __restrict__ b, void* __restrict__ Y, int nrows) {
    int row = blockIdx.x * 4 + (threadIdx.x >> 6);
    if (row >= nrows) return;
    int lane = threadIdx.x & 63;
    const float* xr = X + (long)row * Dm;
    float v[6], s = 0.f;
    #pragma unroll
    for (int i = 0; i < 6; i++) { v[i] = xr[lane + 64 * i]; s += v[i]; }
    for (int off = 32; off; off >>= 1) s += __shfl_down(s, off);
    s = __shfl(s, 0);
    float mu = s / (float)Dm, vs = 0.f;
    #pragma unroll
    for (int i = 0; i < 6; i++) { float d = v[i] - mu; vs += d * d; }
    for (int off = 32; off; off >>= 1) vs += __shfl_down(vs, off);
    vs = __shfl(vs, 0);
    float rs = rsqrtf(vs / (float)Dm + 1e-6f);
    #pragma unroll
    for (int i = 0; i < 6; i++) {
        int c = lane + 64 * i;
        float o = (v[i] - mu) * rs * g[c] + b[c];
        if (OUT_BF16) ((u16*)Y)[(long)row * Dm + c] = f2bf(o);
        else          ((float*)Y)[(long)row * Dm + c] = o;
    }
}

// ---------------- rope apply + pack q/k/v to bf16 ----------------------------
// Qb, Kb: (B*H, 544, 64) row = token; Vt: (B*H, 64, 544) transposed
__global__ void k_ropepack(const float* __restrict__ qkv, const float* __restrict__ ct,
                           const float* __restrict__ st, u16* __restrict__ Qb,
                           u16* __restrict__ Kb, u16* __restrict__ Vt) {
    long tid = (long)blockIdx.x * 256 + threadIdx.x;   // over 24*544*32
    if (tid >= (long)24 * LPAD * 32) return;
    int p = tid & 31;
    long r = tid >> 5;
    int n = r % LPAD; long bh = r / LPAD;
    int b = bh / NHEADS, h = bh % NHEADS;
    float q0 = 0, q1 = 0, k0 = 0, k1 = 0, v0 = 0, v1 = 0;
    if (n < LSEQ) {
        const float* base = qkv + ((long)(b * LSEQ + n) * 1152 + h * HDh + 2 * p);
        q0 = base[0];   q1 = base[1];
        k0 = base[384]; k1 = base[385];
        v0 = base[768]; v1 = base[769];
        if (n >= NMETA) {
            int j = n - NMETA;
            float c = ct[j * 32 + p], s = st[j * 32 + p], a;
            a = q0 * c - q1 * s; q1 = q0 * s + q1 * c; q0 = a;
            a = k0 * c - k1 * s; k1 = k0 * s + k1 * c; k0 = a;
        }
    }
    long qo = (bh * LPAD + n) * (long)HDh + 2 * p;
    Qb[qo] = f2bf(q0); Qb[qo + 1] = f2bf(q1);
    Kb[qo] = f2bf(k0); Kb[qo + 1] = f2bf(k1);
    long vo = (bh * (long)HDh + 2 * p) * LPAD + n;
    Vt[vo] = f2bf(v0); Vt[vo + LPAD] = f2bf(v1);
}

// ---------------- softmax over S rows (scale folded in), write bf16 P --------
__global__ __launch_bounds__(256)
void k_softmax(const float* __restrict__ S, u16* __restrict__ P) {
    int row = blockIdx.x * 4 + (threadIdx.x >> 6);     // 0 .. 24*515-1
    if (row >= 24 * LSEQ) return;
    int lane = threadIdx.x & 63;
    const float* sr = S + (long)row * LPAD;
    float v[9], m = -1e30f;
    #pragma unroll
    for (int i = 0; i < 9; i++) {
        int c = lane + 64 * i;
        v[i] = (c < LSEQ) ? sr[c] * 0.125f : -1e30f;
        m = fmaxf(m, v[i]);
    }
    for (int off = 32; off; off >>= 1) m = fmaxf(m, __shfl_down(m, off));
    m = __shfl(m, 0);
    float sum = 0.f;
    #pragma unroll
    for (int i = 0; i < 9; i++) { v[i] = (v[i] > -1e29f) ? expf(v[i] - m) : 0.f; sum += v[i]; }
    for (int off = 32; off; off >>= 1) sum += __shfl_down(sum, off);
    sum = __shfl(sum, 0);
    float inv = 1.0f / sum;
    u16* pr = P + (long)row * LPAD;
    #pragma unroll
    for (int i = 0; i < 9; i++) {
        int c = lane + 64 * i;
        if (c < LPAD) pr[c] = f2bf((c < LSEQ) ? v[i] * inv : 0.0f);
    }
}

// ---------------- generic batched bf16 MFMA GEMM -----------------------------
// C[m][n] = epi( sum_k A[m][k] * Bt[n][k] + bias[n] )
// 64x64 block tile, BK=32, 4 waves (2x2), each wave 2x2 frags of 16x16x32.
template<int EPI>
__global__ __launch_bounds__(256)
void k_gemm(const u16* __restrict__ A, int lda, long sA, int M,
            const u16* __restrict__ Bt, int ldb, long sB, int btRows,
            void* __restrict__ Cptr, int ldc, long sCz1, long sCz2, int hdiv,
            const float* __restrict__ bias, const float* __restrict__ gamma,
            int N, int K) {
    __shared__ u16 Al[64][40];
    __shared__ u16 Bl[64][40];
    int z = blockIdx.z;
    const u16* Ab = A + (long)z * sA;
    const u16* Bb = Bt + (long)z * sB;
    long coff = (long)(z / hdiv) * sCz1 + (long)(z % hdiv) * sCz2;
    int row0 = blockIdx.x * 64, col0 = blockIdx.y * 64;
    int t = threadIdx.x;
    int lane = t & 63, w = t >> 6;
    int wr = (w >> 1) * 32, wc = (w & 1) * 32;
    int srow = t >> 2, skq = (t & 3) * 8;
    f32x4 acc[2][2] = {};
    for (int kk = 0; kk < K; kk += 32) {
        uint4 av = make_uint4(0, 0, 0, 0), bv = make_uint4(0, 0, 0, 0);
        if (row0 + srow < M)      av = *(const uint4*)(Ab + (long)(row0 + srow) * lda + kk + skq);
        if (col0 + srow < btRows) bv = *(const uint4*)(Bb + (long)(col0 + srow) * ldb + kk + skq);
        __syncthreads();
        *(uint4*)(&Al[srow][skq]) = av;
        *(uint4*)(&Bl[srow][skq]) = bv;
        __syncthreads();
        int fr = lane & 15, kg = (lane >> 4) * 8;
        bf16x8 af[2], bg[2];
        #pragma unroll
        for (int i = 0; i < 2; i++) {
            af[i] = *(const bf16x8*)(&Al[wr + 16 * i + fr][kg]);
            bg[i] = *(const bf16x8*)(&Bl[wc + 16 * i + fr][kg]);
        }
        #pragma unroll
        for (int mi = 0; mi < 2; mi++)
            #pragma unroll
            for (int nj = 0; nj < 2; nj++)
                acc[mi][nj] = __builtin_amdgcn_mfma_f32_16x16x32_bf16(af[mi], bg[nj], acc[mi][nj], 0, 0, 0);
    }
    int fr = lane & 15, rg = (lane >> 4) * 4;
    #pragma unroll
    for (int mi = 0; mi < 2; mi++)
        #pragma unroll
        for (int nj = 0; nj < 2; nj++)
            #pragma unroll
            for (int r = 0; r < 4; r++) {
                int row = row0 + wr + 16 * mi + rg + r;
                int col = col0 + wc + 16 * nj + fr;
                if (row >= M || col >= N) continue;
                float v = acc[mi][nj][r];
                if (bias) v += bias[col];
                long idx = coff + (long)row * ldc + col;
                if (EPI == EPI_F32)      ((float*)Cptr)[idx] = v;
                else if (EPI == EPI_BF16)((u16*)Cptr)[idx] = f2bf(v);
                else if (EPI == EPI_GELU) {
                    v = 0.5f * v * (1.0f + erff(v * 0.70710678118f));
                    ((u16*)Cptr)[idx] = f2bf(v);
                } else { // EPI_RES (in-place residual on f32 C)
                    float* C = (float*)Cptr;
                    C[idx] = C[idx] + gamma[col] * v;
                }
            }
}

// ---------------- host orchestration -----------------------------------------
extern "C" void kernel_launch(void* const* d_in, const int* in_sizes, int n_in,
                              void* d_out, int out_size, void* d_ws, size_t ws_size,
                              hipStream_t stream) {
    const float* x        = (const float*)d_in[0];
    const float* means    = (const float*)d_in[1];
    const float* stds     = (const float*)d_in[2];
    const int*   channels = (const int*)  d_in[3];
    const float* noise    = (const float*)d_in[4];
    const int*   win_size = (const int*)  d_in[5];
    // d_in[6] = mask_ratio (0)
    const float* patch_w  = (const float*)d_in[7];
    const float* patch_b  = (const float*)d_in[8];
    const float* cls_tok  = (const float*)d_in[9];
    const float* chan_tab = (const float*)d_in[10];
    const float* mean_w   = (const float*)d_in[11];
    const float* mean_b   = (const float*)d_in[12];
    const float* qkv_w    = (const float*)d_in[13];
    const float* qkv_b    = (const float*)d_in[14];
    const float* proj_w   = (const float*)d_in[15];
    const float* proj_b   = (const float*)d_in[16];
    const float* fc1_w    = (const float*)d_in[17];
    const float* fc1_b    = (const float*)d_in[18];
    const float* fc2_w    = (const float*)d_in[19];
    const float* fc2_b    = (const float*)d_in[20];
    const float* ln1_g    = (const float*)d_in[21];
    const float* ln1_b    = (const float*)d_in[22];
    const float* ln2_g    = (const float*)d_in[23];
    const float* ln2_b    = (const float*)d_in[24];
    const float* gamma1   = (const float*)d_in[25];
    const float* gamma2   = (const float*)d_in[26];
    const float* lnf_g    = (const float*)d_in[27];
    const float* lnf_b    = (const float*)d_in[28];
    float* out = (float*)d_out;

    char* wp = (char*)d_ws;
    auto alloc = [&](size_t bytes) { char* p = wp; wp += (bytes + 255) & ~(size_t)255; return p; };
    u16*   qkvT  = (u16*)  alloc((size_t)NDEPTH * 1152 * 384 * 2);
    u16*   projT = (u16*)  alloc((size_t)NDEPTH * 384 * 384 * 2);
    u16*   fc1T  = (u16*)  alloc((size_t)NDEPTH * 1536 * 384 * 2);
    u16*   fc2T  = (u16*)  alloc((size_t)NDEPTH * 384 * 1536 * 2);
    float* xt    = (float*)alloc((size_t)Bq * LSEQ * Dm * 4);
    u16*   yb    = (u16*)  alloc((size_t)Bq * LSEQ * Dm * 2);
    float* qkvb  = (float*)alloc((size_t)Bq * LSEQ * 1152 * 4);
    u16*   Qb    = (u16*)  alloc((size_t)24 * LPAD * HDh * 2);
    u16*   Kb    = (u16*)  alloc((size_t)24 * LPAD * HDh * 2);
    u16*   Vt    = (u16*)  alloc((size_t)24 * HDh * LPAD * 2);
    float* S     = (float*)alloc((size_t)24 * LSEQ * LPAD * 4);
    u16*   P     = (u16*)  alloc((size_t)24 * LSEQ * LPAD * 2);
    u16*   obuf  = (u16*)  alloc((size_t)Bq * LSEQ * Dm * 2);
    u16*   hid   = (u16*)  alloc((size_t)Bq * LSEQ * 1536 * 2);
    float* tmp   = (float*)alloc((size_t)Bq * NPATCH * Dm * 4);
    float* ct    = (float*)alloc((size_t)NPATCH * 32 * 4);
    float* st    = (float*)alloc((size_t)NPATCH * 32 * 4);
    int*   ids   = (int*)  alloc((size_t)Bq * NPATCH * 4);

    // weights -> bf16 transposed
    k_transpose<<<dim3(1152 / 32, 384 / 32, NDEPTH), 256, 0, stream>>>(qkv_w, qkvT, 384, 1152);
    k_transpose<<<dim3(384 / 32, 384 / 32, NDEPTH), 256, 0, stream>>>(proj_w, projT, 384, 384);
    k_transpose<<<dim3(1536 / 32, 384 / 32, NDEPTH), 256, 0, stream>>>(fc1_w, fc1T, 384, 1536);
    k_transpose<<<dim3(384 / 32, 1536 / 32, NDEPTH), 256, 0, stream>>>(fc2_w, fc2T, 1536, 384);

    // build initial xt
    k_patch<<<Bq * NPATCH, 256, 0, stream>>>(x, patch_w, patch_b, channels, chan_tab, tmp);
    k_argsort<<<Bq, 512, 0, stream>>>(noise, ids);
    k_gather<<<(Bq * NPATCH * Dm + 255) / 256, 256, 0, stream>>>(tmp, ids, xt);
    k_meta<<<16, 192, 0, stream>>>(means, stds, mean_w, mean_b, xt);
    k_cls<<<(Bq * Dm + 255) / 256, 256, 0, stream>>>(cls_tok, xt);
    k_outextra<<<(4608 + 2048 + 1 + 255) / 256, 256, 0, stream>>>(xt, out);
    k_ropetab<<<(NPATCH * 32 + 255) / 256, 256, 0, stream>>>(win_size, ct, st);

    const int ROWS = Bq * LSEQ;        // 2060
    const int MT = (ROWS + 63) / 64;   // 33
    const int NT_S = (LPAD + 63) / 64; // 9  (FIX: was LPAD/64 == 8, dropped key cols 512..543)
    for (int d = 0; d < NDEPTH; d++) {
        k_ln<true><<<(ROWS + 3) / 4, 256, 0, stream>>>(xt, ln1_g + d * Dm, ln1_b + d * Dm, yb, ROWS);
        // qkv: (2060 x 384) @ (384 x 1152) + b -> f32
        k_gemm<EPI_F32><<<dim3(MT, 1152 / 64, 1), 256, 0, stream>>>(
            yb, Dm, 0, ROWS,
            qkvT + (long)d * 1152 * 384, 384, 0, 1152,
            qkvb, 1152, 0, 0, 1,
            qkv_b + d * 1152, nullptr, 1152, 384);
        k_ropepack<<<(24 * LPAD * 32 + 255) / 256, 256, 0, stream>>>(qkvb, ct, st, Qb, Kb, Vt);
        // S = Q @ K^T : batched 24, M=515, N=544(padded), K=64
        k_gemm<EPI_F32><<<dim3((LSEQ + 63) / 64, NT_S, 24), 256, 0, stream>>>(
            Qb, HDh, (long)LPAD * HDh, LSEQ,
            Kb, HDh, (long)LPAD * HDh, LPAD,
            S, LPAD, (long)LSEQ * LPAD, 0, 1,
            nullptr, nullptr, LPAD, HDh);
        k_softmax<<<(24 * LSEQ + 3) / 4, 256, 0, stream>>>(S, P);
        // O = P @ V : batched 24, M=515, N=64, K=544 -> obuf (B, L, 384) bf16
        k_gemm<EPI_BF16><<<dim3((LSEQ + 63) / 64, 1, 24), 256, 0, stream>>>(
            P, LPAD, (long)LSEQ * LPAD, LSEQ,
            Vt, LPAD, (long)HDh * LPAD, HDh,
            obuf, Dm, (long)LSEQ * Dm, HDh, NHEADS,
            nullptr, nullptr, HDh, LPAD);
        // proj + gamma1 residual into xt
        k_gemm<EPI_RES><<<dim3(MT, Dm / 64, 1), 256, 0, stream>>>(
            obuf, Dm, 0, ROWS,
            projT + (long)d * 384 * 384, 384, 0, 384,
            xt, Dm, 0, 0, 1,
            proj_b + d * Dm, gamma1 + d * Dm, Dm, 384);
        k_ln<true><<<(ROWS + 3) / 4, 256, 0, stream>>>(xt, ln2_g + d * Dm, ln2_b + d * Dm, yb, ROWS);
        // fc1 + gelu -> hid bf16
        k_gemm<EPI_GELU><<<dim3(MT, 1536 / 64, 1), 256, 0, stream>>>(
            yb, Dm, 0, ROWS,
            fc1T + (long)d * 1536 * 384, 384, 0, 1536,
            hid, 1536, 0, 0, 1,
            fc1_b + d * 1536, nullptr, 1536, 384);
        // fc2 + gamma2 residual into xt
        k_gemm<EPI_RES><<<dim3(MT, Dm / 64, 1), 256, 0, stream>>>(
            hid, 1536, 0, ROWS,
            fc2T + (long)d * 384 * 1536, 1536, 0, 384,
            xt, Dm, 0, 0, 1,
            fc2_b + d * Dm, gamma2 + d * Dm, Dm, 1536);
    }
    // final layernorm -> d_out (f32)
    k_ln<false><<<(ROWS + 3) / 4, 256, 0, stream>>>(xt, lnf_g, lnf_b, out, ROWS);
}

// Round 3
// 1689.145 us; speedup vs baseline: 1.1943x; 1.1943x over previous
//
#include <hip/hip_runtime.h>
#include <hip/hip_bf16.h>
#include <math.h>

// ---------------- constants ----------------
#define Bq     4
#define LSEQ   515          // 3 meta + 512 data tokens
#define NMETA  3
#define NPATCH 512
#define Dm     384
#define NHEADS 6
#define HDh    64
#define NDEPTH 12
#define LPAD   544          // 515 padded to multiple of 32
#define KSPL   32           // split-K chunks for meta GEMM
#define KCH    125          // 4000 / KSPL

typedef unsigned short u16;
typedef short bf16x8 __attribute__((ext_vector_type(8)));
typedef float f32x4  __attribute__((ext_vector_type(4)));

enum { EPI_F32 = 0, EPI_BF16 = 1, EPI_GELU = 2, EPI_RES = 3 };

__device__ inline u16 f2bf(float x) {
    __hip_bfloat16 h = __float2bfloat16(x);
    return *reinterpret_cast<u16*>(&h);
}

// ---------------- weight transpose + cast: W (R x C) f32 -> WT (C x R) bf16, per layer z ----
__global__ __launch_bounds__(256)
void k_transpose(const float* __restrict__ W, u16* __restrict__ WT, int R, int C) {
    __shared__ float tile[32][33];
    int z = blockIdx.z;
    const float* Wz = W + (long)z * R * C;
    u16* Tz = WT + (long)z * R * C;
    int c0 = blockIdx.x * 32, r0 = blockIdx.y * 32;
    int tx = threadIdx.x & 31, ty = threadIdx.x >> 5;     // 32 x 8
    for (int rr = ty; rr < 32; rr += 8)
        tile[rr][tx] = Wz[(long)(r0 + rr) * C + c0 + tx];
    __syncthreads();
    for (int rr = ty; rr < 32; rr += 8)
        Tz[(long)(c0 + rr) * R + r0 + tx] = f2bf(tile[tx][rr]);
}

// ---------------- patch embed (fp32): one block per patch --------------------
__global__ __launch_bounds__(256)
void k_patch(const float* __restrict__ x, const float* __restrict__ pw,
             const float* __restrict__ pb, const int* __restrict__ chan,
             const float* __restrict__ ctab, float* __restrict__ tmp) {
    __shared__ float px[256];
    int m = blockIdx.x;               // 0..2047  (b*512 + n)
    int b = m >> 9, n = m & 511;
    int i = n >> 6, j = n & 63;       // patch grid 8 x 64
    int t = threadIdx.x;
    int pr = t >> 4, pc = t & 15;
    px[t] = x[(long)b * 131072 + (i * 16 + pr) * 1024 + j * 16 + pc];
    __syncthreads();
    int ch = chan[m];
    for (int d = t; d < Dm; d += 256) {
        const float* wr_ = pw + (long)d * 256;
        float a = 0.f;
        #pragma unroll 8
        for (int k = 0; k < 256; k++) a += px[k] * wr_[k];
        tmp[(long)m * Dm + d] = a + pb[d] + ctab[(long)ch * Dm + d];
    }
}

// ---------------- stable argsort of noise rows (512) via bitonic w/ index tie-break ----
__global__ __launch_bounds__(512)
void k_argsort(const float* __restrict__ noise, int* __restrict__ ids) {
    __shared__ float v[512];
    __shared__ int   ix[512];
    int b = blockIdx.x, t = threadIdx.x;
    v[t] = noise[b * 512 + t]; ix[t] = t;
    __syncthreads();
    for (int k = 2; k <= 512; k <<= 1)
        for (int j = k >> 1; j > 0; j >>= 1) {
            int p = t ^ j;
            if (p > t) {
                bool up = (t & k) == 0;
                float va = v[t], vb = v[p]; int ia = ix[t], ib = ix[p];
                bool sw = (va > vb) || (va == vb && ia > ib);
                if (sw == up) { v[t] = vb; v[p] = va; ix[t] = ib; ix[p] = ia; }
            }
            __syncthreads();
        }
    ids[b * 512 + t] = ix[t];
}

// ---------------- gather data tokens into xt rows [3..514] -------------------
__global__ void k_gather(const float* __restrict__ tmp, const int* __restrict__ ids,
                         float* __restrict__ xt) {
    long t = (long)blockIdx.x * 256 + threadIdx.x;
    if (t >= (long)Bq * NPATCH * Dm) return;
    int d = t % Dm; long r = t / Dm;
    int j = r % NPATCH, b = r / NPATCH;
    int src = ids[b * NPATCH + j];
    xt[((long)b * LSEQ + NMETA + j) * Dm + d] = tmp[((long)b * NPATCH + src) * Dm + d];
}

// ---------------- meta tokens, split-K stage 1: partial[g][c][d] --------------
// g = b(4) x mi(2) x part(2); c = K-chunk (32 x 125); d = 0..191
__global__ __launch_bounds__(192)
void k_meta1(const float* __restrict__ means, const float* __restrict__ stds,
             const float* __restrict__ mw, float* __restrict__ part) {
    int g = blockIdx.x, c = blockIdx.y;
    int d = threadIdx.x;
    int p = g & 1, mi = (g >> 1) & 1, b = g >> 2;
    const float* row = (p ? stds : means) + (long)(b * 2 + mi) * 4000 + c * KCH;
    const float* w = mw + (long)c * KCH * 192 + d;
    float a = 0.f;
    #pragma unroll 5
    for (int k = 0; k < KCH; k++) a += row[k] * w[(long)k * 192];
    part[((long)g * KSPL + c) * 192 + d] = a;
}

// ---------------- meta stage 2: reduce partials + bias -> xt rows 1,2 ---------
__global__ __launch_bounds__(192)
void k_meta2(const float* __restrict__ part, const float* __restrict__ mb,
             float* __restrict__ xt) {
    int g = blockIdx.x, d = threadIdx.x;
    int p = g & 1, mi = (g >> 1) & 1, b = g >> 2;
    float a = mb[d];
    #pragma unroll 8
    for (int c = 0; c < KSPL; c++) a += part[((long)g * KSPL + c) * 192 + d];
    xt[((long)b * LSEQ + 1 + mi) * Dm + p * 192 + d] = a;
}

// ---------------- cls row ----------------------------------------------------
__global__ void k_cls(const float* __restrict__ cls, float* __restrict__ xt) {
    int t = blockIdx.x * 256 + threadIdx.x;
    if (t >= Bq * Dm) return;
    int b = t / Dm, d = t % Dm;
    xt[(long)b * LSEQ * Dm + d] = cls[d];
}

// ---------------- meta_patches / mask / n_meta outputs -----------------------
__global__ void k_outextra(const float* __restrict__ xt, float* __restrict__ out) {
    int t = blockIdx.x * 256 + threadIdx.x;
    const int META = Bq * NMETA * Dm;          // 4608
    const int MASKN = Bq * NPATCH;             // 2048
    if (t < META) {
        int d = t % Dm; int r = t / Dm; int b = r / NMETA, mi = r % NMETA;
        out[791040 + t] = xt[((long)b * LSEQ + mi) * Dm + d];
    } else if (t < META + MASKN) {
        out[791040 + t] = 0.0f;                // mask (len_keep == 512)
    } else if (t == META + MASKN) {
        out[791040 + t] = 3.0f;                // n_meta
    }
}

// ---------------- RoPE cos/sin table -----------------------------------------
__global__ void k_ropetab(const int* __restrict__ win, float* __restrict__ ct,
                          float* __restrict__ st) {
    int t = blockIdx.x * 256 + threadIdx.x;
    if (t >= NPATCH * 32) return;
    int p = t & 31, n = t >> 5;
    int i = n >> 6, j = n & 63;
    float step = (float)(*win) * 0.25f / 0.125f;
    float inv, ang;
    if (p < 16) { inv = powf(100.0f, -(float)p / 16.0f);        ang = (float)j * step * inv; }
    else        { inv = powf(100.0f, -(float)(p - 16) / 16.0f); ang = (float)i * inv; }
    ct[t] = cosf(ang); st[t] = sinf(ang);
}

// ---------------- layernorm: 1 wave per row, D=384 ---------------------------
template<bool OUT_BF16>
__global__ __launch_bounds__(256)
void k_ln(const float* __restrict__ X, const float* __restrict__ g,
          const float* __restrict__ b, void* __restrict__ Y, int nrows) {
    int row = blockIdx.x * 4 + (threadIdx.x >> 6);
    if (row >= nrows) return;
    int lane = threadIdx.x & 63;
    const float* xr = X + (long)row * Dm;
    float v[6], s = 0.f;
    #pragma unroll
    for (int i = 0; i < 6; i++) { v[i] = xr[lane + 64 * i]; s += v[i]; }
    for (int off = 32; off; off >>= 1) s += __shfl_down(s, off);
    s = __shfl(s, 0);
    float mu = s / (float)Dm, vs = 0.f;
    #pragma unroll
    for (int i = 0; i < 6; i++) { float d = v[i] - mu; vs += d * d; }
    for (int off = 32; off; off >>= 1) vs += __shfl_down(vs, off);
    vs = __shfl(vs, 0);
    float rs = rsqrtf(vs / (float)Dm + 1e-6f);
    #pragma unroll
    for (int i = 0; i < 6; i++) {
        int c = lane + 64 * i;
        float o = (v[i] - mu) * rs * g[c] + b[c];
        if (OUT_BF16) ((u16*)Y)[(long)row * Dm + c] = f2bf(o);
        else          ((float*)Y)[(long)row * Dm + c] = o;
    }
}

// ---------------- rope apply + pack q/k/v to bf16 ----------------------------
// Qb, Kb: (B*H, 544, 64) row = token; Vt: (B*H, 64, 544) transposed
__global__ void k_ropepack(const float* __restrict__ qkv, const float* __restrict__ ct,
                           const float* __restrict__ st, u16* __restrict__ Qb,
                           u16* __restrict__ Kb, u16* __restrict__ Vt) {
    long tid = (long)blockIdx.x * 256 + threadIdx.x;   // over 24*544*32
    if (tid >= (long)24 * LPAD * 32) return;
    int p = tid & 31;
    long r = tid >> 5;
    int n = r % LPAD; long bh = r / LPAD;
    int b = bh / NHEADS, h = bh % NHEADS;
    float q0 = 0, q1 = 0, k0 = 0, k1 = 0, v0 = 0, v1 = 0;
    if (n < LSEQ) {
        const float* base = qkv + ((long)(b * LSEQ + n) * 1152 + h * HDh + 2 * p);
        q0 = base[0];   q1 = base[1];
        k0 = base[384]; k1 = base[385];
        v0 = base[768]; v1 = base[769];
        if (n >= NMETA) {
            int j = n - NMETA;
            float c = ct[j * 32 + p], s = st[j * 32 + p], a;
            a = q0 * c - q1 * s; q1 = q0 * s + q1 * c; q0 = a;
            a = k0 * c - k1 * s; k1 = k0 * s + k1 * c; k0 = a;
        }
    }
    long qo = (bh * LPAD + n) * (long)HDh + 2 * p;
    Qb[qo] = f2bf(q0); Qb[qo + 1] = f2bf(q1);
    Kb[qo] = f2bf(k0); Kb[qo + 1] = f2bf(k1);
    long vo = (bh * (long)HDh + 2 * p) * LPAD + n;
    Vt[vo] = f2bf(v0); Vt[vo + LPAD] = f2bf(v1);
}

// ---------------- softmax over S rows (scale folded in), write bf16 P --------
__global__ __launch_bounds__(256)
void k_softmax(const float* __restrict__ S, u16* __restrict__ P) {
    int row = blockIdx.x * 4 + (threadIdx.x >> 6);     // 0 .. 24*515-1
    if (row >= 24 * LSEQ) return;
    int lane = threadIdx.x & 63;
    const float* sr = S + (long)row * LPAD;
    float v[9], m = -1e30f;
    #pragma unroll
    for (int i = 0; i < 9; i++) {
        int c = lane + 64 * i;
        v[i] = (c < LSEQ) ? sr[c] * 0.125f : -1e30f;
        m = fmaxf(m, v[i]);
    }
    for (int off = 32; off; off >>= 1) m = fmaxf(m, __shfl_down(m, off));
    m = __shfl(m, 0);
    float sum = 0.f;
    #pragma unroll
    for (int i = 0; i < 9; i++) { v[i] = (v[i] > -1e29f) ? expf(v[i] - m) : 0.f; sum += v[i]; }
    for (int off = 32; off; off >>= 1) sum += __shfl_down(sum, off);
    sum = __shfl(sum, 0);
    float inv = 1.0f / sum;
    u16* pr = P + (long)row * LPAD;
    #pragma unroll
    for (int i = 0; i < 9; i++) {
        int c = lane + 64 * i;
        if (c < LPAD) pr[c] = f2bf((c < LSEQ) ? v[i] * inv : 0.0f);
    }
}

// ---------------- generic batched bf16 MFMA GEMM -----------------------------
// C[m][n] = epi( sum_k A[m][k] * Bt[n][k] + bias[n] )
// 64x64 block tile, BK=32, 4 waves (2x2), each wave 2x2 frags of 16x16x32.
template<int EPI>
__global__ __launch_bounds__(256)
void k_gemm(const u16* __restrict__ A, int lda, long sA, int M,
            const u16* __restrict__ Bt, int ldb, long sB, int btRows,
            void* __restrict__ Cptr, int ldc, long sCz1, long sCz2, int hdiv,
            const float* __restrict__ bias, const float* __restrict__ gamma,
            int N, int K) {
    __shared__ u16 Al[64][40];
    __shared__ u16 Bl[64][40];
    int z = blockIdx.z;
    const u16* Ab = A + (long)z * sA;
    const u16* Bb = Bt + (long)z * sB;
    long coff = (long)(z / hdiv) * sCz1 + (long)(z % hdiv) * sCz2;
    int row0 = blockIdx.x * 64, col0 = blockIdx.y * 64;
    int t = threadIdx.x;
    int lane = t & 63, w = t >> 6;
    int wr = (w >> 1) * 32, wc = (w & 1) * 32;
    int srow = t >> 2, skq = (t & 3) * 8;
    f32x4 acc[2][2] = {};
    for (int kk = 0; kk < K; kk += 32) {
        uint4 av = make_uint4(0, 0, 0, 0), bv = make_uint4(0, 0, 0, 0);
        if (row0 + srow < M)      av = *(const uint4*)(Ab + (long)(row0 + srow) * lda + kk + skq);
        if (col0 + srow < btRows) bv = *(const uint4*)(Bb + (long)(col0 + srow) * ldb + kk + skq);
        __syncthreads();
        *(uint4*)(&Al[srow][skq]) = av;
        *(uint4*)(&Bl[srow][skq]) = bv;
        __syncthreads();
        int fr = lane & 15, kg = (lane >> 4) * 8;
        bf16x8 af[2], bg[2];
        #pragma unroll
        for (int i = 0; i < 2; i++) {
            af[i] = *(const bf16x8*)(&Al[wr + 16 * i + fr][kg]);
            bg[i] = *(const bf16x8*)(&Bl[wc + 16 * i + fr][kg]);
        }
        #pragma unroll
        for (int mi = 0; mi < 2; mi++)
            #pragma unroll
            for (int nj = 0; nj < 2; nj++)
                acc[mi][nj] = __builtin_amdgcn_mfma_f32_16x16x32_bf16(af[mi], bg[nj], acc[mi][nj], 0, 0, 0);
    }
    int fr = lane & 15, rg = (lane >> 4) * 4;
    #pragma unroll
    for (int mi = 0; mi < 2; mi++)
        #pragma unroll
        for (int nj = 0; nj < 2; nj++)
            #pragma unroll
            for (int r = 0; r < 4; r++) {
                int row = row0 + wr + 16 * mi + rg + r;
                int col = col0 + wc + 16 * nj + fr;
                if (row >= M || col >= N) continue;
                float v = acc[mi][nj][r];
                if (bias) v += bias[col];
                long idx = coff + (long)row * ldc + col;
                if (EPI == EPI_F32)      ((float*)Cptr)[idx] = v;
                else if (EPI == EPI_BF16)((u16*)Cptr)[idx] = f2bf(v);
                else if (EPI == EPI_GELU) {
                    v = 0.5f * v * (1.0f + erff(v * 0.70710678118f));
                    ((u16*)Cptr)[idx] = f2bf(v);
                } else { // EPI_RES (in-place residual on f32 C)
                    float* C = (float*)Cptr;
                    C[idx] = C[idx] + gamma[col] * v;
                }
            }
}

// ---------------- host orchestration -----------------------------------------
extern "C" void kernel_launch(void* const* d_in, const int* in_sizes, int n_in,
                              void* d_out, int out_size, void* d_ws, size_t ws_size,
                              hipStream_t stream) {
    const float* x        = (const float*)d_in[0];
    const float* means    = (const float*)d_in[1];
    const float* stds     = (const float*)d_in[2];
    const int*   channels = (const int*)  d_in[3];
    const float* noise    = (const float*)d_in[4];
    const int*   win_size = (const int*)  d_in[5];
    // d_in[6] = mask_ratio (0)
    const float* patch_w  = (const float*)d_in[7];
    const float* patch_b  = (const float*)d_in[8];
    const float* cls_tok  = (const float*)d_in[9];
    const float* chan_tab = (const float*)d_in[10];
    const float* mean_w   = (const float*)d_in[11];
    const float* mean_b   = (const float*)d_in[12];
    const float* qkv_w    = (const float*)d_in[13];
    const float* qkv_b    = (const float*)d_in[14];
    const float* proj_w   = (const float*)d_in[15];
    const float* proj_b   = (const float*)d_in[16];
    const float* fc1_w    = (const float*)d_in[17];
    const float* fc1_b    = (const float*)d_in[18];
    const float* fc2_w    = (const float*)d_in[19];
    const float* fc2_b    = (const float*)d_in[20];
    const float* ln1_g    = (const float*)d_in[21];
    const float* ln1_b    = (const float*)d_in[22];
    const float* ln2_g    = (const float*)d_in[23];
    const float* ln2_b    = (const float*)d_in[24];
    const float* gamma1   = (const float*)d_in[25];
    const float* gamma2   = (const float*)d_in[26];
    const float* lnf_g    = (const float*)d_in[27];
    const float* lnf_b    = (const float*)d_in[28];
    float* out = (float*)d_out;

    char* wp = (char*)d_ws;
    auto alloc = [&](size_t bytes) { char* p = wp; wp += (bytes + 255) & ~(size_t)255; return p; };
    u16*   qkvT  = (u16*)  alloc((size_t)NDEPTH * 1152 * 384 * 2);
    u16*   projT = (u16*)  alloc((size_t)NDEPTH * 384 * 384 * 2);
    u16*   fc1T  = (u16*)  alloc((size_t)NDEPTH * 1536 * 384 * 2);
    u16*   fc2T  = (u16*)  alloc((size_t)NDEPTH * 384 * 1536 * 2);
    float* xt    = (float*)alloc((size_t)Bq * LSEQ * Dm * 4);
    u16*   yb    = (u16*)  alloc((size_t)Bq * LSEQ * Dm * 2);
    float* qkvb  = (float*)alloc((size_t)Bq * LSEQ * 1152 * 4);
    u16*   Qb    = (u16*)  alloc((size_t)24 * LPAD * HDh * 2);
    u16*   Kb    = (u16*)  alloc((size_t)24 * LPAD * HDh * 2);
    u16*   Vt    = (u16*)  alloc((size_t)24 * HDh * LPAD * 2);
    float* S     = (float*)alloc((size_t)24 * LSEQ * LPAD * 4);
    u16*   P     = (u16*)  alloc((size_t)24 * LSEQ * LPAD * 2);
    u16*   obuf  = (u16*)  alloc((size_t)Bq * LSEQ * Dm * 2);
    u16*   hid   = (u16*)  alloc((size_t)Bq * LSEQ * 1536 * 2);
    float* tmp   = (float*)alloc((size_t)Bq * NPATCH * Dm * 4);
    float* ct    = (float*)alloc((size_t)NPATCH * 32 * 4);
    float* st    = (float*)alloc((size_t)NPATCH * 32 * 4);
    int*   ids   = (int*)  alloc((size_t)Bq * NPATCH * 4);
    float* mpart = (float*)alloc((size_t)16 * KSPL * 192 * 4);

    // weights -> bf16 transposed
    k_transpose<<<dim3(1152 / 32, 384 / 32, NDEPTH), 256, 0, stream>>>(qkv_w, qkvT, 384, 1152);
    k_transpose<<<dim3(384 / 32, 384 / 32, NDEPTH), 256, 0, stream>>>(proj_w, projT, 384, 384);
    k_transpose<<<dim3(1536 / 32, 384 / 32, NDEPTH), 256, 0, stream>>>(fc1_w, fc1T, 384, 1536);
    k_transpose<<<dim3(384 / 32, 1536 / 32, NDEPTH), 256, 0, stream>>>(fc2_w, fc2T, 1536, 384);

    // build initial xt
    k_patch<<<Bq * NPATCH, 256, 0, stream>>>(x, patch_w, patch_b, channels, chan_tab, tmp);
    k_argsort<<<Bq, 512, 0, stream>>>(noise, ids);
    k_gather<<<(Bq * NPATCH * Dm + 255) / 256, 256, 0, stream>>>(tmp, ids, xt);
    k_meta1<<<dim3(16, KSPL), 192, 0, stream>>>(means, stds, mean_w, mpart);
    k_meta2<<<16, 192, 0, stream>>>(mpart, mean_b, xt);
    k_cls<<<(Bq * Dm + 255) / 256, 256, 0, stream>>>(cls_tok, xt);
    k_outextra<<<(4608 + 2048 + 1 + 255) / 256, 256, 0, stream>>>(xt, out);
    k_ropetab<<<(NPATCH * 32 + 255) / 256, 256, 0, stream>>>(win_size, ct, st);

    const int ROWS = Bq * LSEQ;        // 2060
    const int MT = (ROWS + 63) / 64;   // 33
    const int NT_S = (LPAD + 63) / 64; // 9
    for (int d = 0; d < NDEPTH; d++) {
        k_ln<true><<<(ROWS + 3) / 4, 256, 0, stream>>>(xt, ln1_g + d * Dm, ln1_b + d * Dm, yb, ROWS);
        // qkv: (2060 x 384) @ (384 x 1152) + b -> f32
        k_gemm<EPI_F32><<<dim3(MT, 1152 / 64, 1), 256, 0, stream>>>(
            yb, Dm, 0, ROWS,
            qkvT + (long)d * 1152 * 384, 384, 0, 1152,
            qkvb, 1152, 0, 0, 1,
            qkv_b + d * 1152, nullptr, 1152, 384);
        k_ropepack<<<(24 * LPAD * 32 + 255) / 256, 256, 0, stream>>>(qkvb, ct, st, Qb, Kb, Vt);
        // S = Q @ K^T : batched 24, M=515, N=544(padded), K=64
        k_gemm<EPI_F32><<<dim3((LSEQ + 63) / 64, NT_S, 24), 256, 0, stream>>>(
            Qb, HDh, (long)LPAD * HDh, LSEQ,
            Kb, HDh, (long)LPAD * HDh, LPAD,
            S, LPAD, (long)LSEQ * LPAD, 0, 1,
            nullptr, nullptr, LPAD, HDh);
        k_softmax<<<(24 * LSEQ + 3) / 4, 256, 0, stream>>>(S, P);
        // O = P @ V : batched 24, M=515, N=64, K=544 -> obuf (B, L, 384) bf16
        k_gemm<EPI_BF16><<<dim3((LSEQ + 63) / 64, 1, 24), 256, 0, stream>>>(
            P, LPAD, (long)LSEQ * LPAD, LSEQ,
            Vt, LPAD, (long)HDh * LPAD, HDh,
            obuf, Dm, (long)LSEQ * Dm, HDh, NHEADS,
            nullptr, nullptr, HDh, LPAD);
        // proj + gamma1 residual into xt
        k_gemm<EPI_RES><<<dim3(MT, Dm / 64, 1), 256, 0, stream>>>(
            obuf, Dm, 0, ROWS,
            projT + (long)d * 384 * 384, 384, 0, 384,
            xt, Dm, 0, 0, 1,
            proj_b + d * Dm, gamma1 + d * Dm, Dm, 384);
        k_ln<true><<<(ROWS + 3) / 4, 256, 0, stream>>>(xt, ln2_g + d * Dm, ln2_b + d * Dm, yb, ROWS);
        // fc1 + gelu -> hid bf16
        k_gemm<EPI_GELU><<<dim3(MT, 1536 / 64, 1), 256, 0, stream>>>(
            yb, Dm, 0, ROWS,
            fc1T + (long)d * 1536 * 384, 384, 0, 1536,
            hid, 1536, 0, 0, 1,
            fc1_b + d * 1536, nullptr, 1536, 384);
        // fc2 + gamma2 residual into xt
        k_gemm<EPI_RES><<<dim3(MT, Dm / 64, 1), 256, 0, stream>>>(
            hid, 1536, 0, ROWS,
            fc2T + (long)d * 384 * 1536, 1536, 0, 384,
            xt, Dm, 0, 0, 1,
            fc2_b + d * Dm, gamma2 + d * Dm, Dm, 1536);
    }
    // final layernorm -> d_out (f32)
    k_ln<false><<<(ROWS + 3) / 4, 256, 0, stream>>>(xt, lnf_g, lnf_b, out, ROWS);
}

// Round 4
// 1614.940 us; speedup vs baseline: 1.2492x; 1.0459x over previous
//
#include <hip/hip_runtime.h>
#include <hip/hip_bf16.h>
#include <math.h>

// ---------------- constants ----------------
#define Bq     4
#define LSEQ   515          // 3 meta + 512 data tokens
#define NMETA  3
#define NPATCH 512
#define Dm     384
#define NHEADS 6
#define HDh    64
#define NDEPTH 12
#define LPAD   544          // 515 padded to multiple of 32
#define KSPL   32           // split-K chunks for meta GEMM
#define KCH    125          // 4000 / KSPL

typedef unsigned short u16;
typedef short bf16x8 __attribute__((ext_vector_type(8)));
typedef float f32x4  __attribute__((ext_vector_type(4)));

enum { EPI_F32 = 0, EPI_BF16 = 1, EPI_GELU = 2, EPI_RES = 3 };

__device__ inline u16 f2bf(float x) {
    __hip_bfloat16 h = __float2bfloat16(x);
    return *reinterpret_cast<u16*>(&h);
}
__device__ inline float bf2f(u16 x) {
    __hip_bfloat16 h = *reinterpret_cast<__hip_bfloat16*>(&x);
    return __bfloat162float(h);
}

// ---------------- weight transpose + cast: W (R x C) f32 -> WT (C x R) bf16, per layer z ----
__global__ __launch_bounds__(256)
void k_transpose(const float* __restrict__ W, u16* __restrict__ WT, int R, int C) {
    __shared__ float tile[32][33];
    int z = blockIdx.z;
    const float* Wz = W + (long)z * R * C;
    u16* Tz = WT + (long)z * R * C;
    int c0 = blockIdx.x * 32, r0 = blockIdx.y * 32;
    int tx = threadIdx.x & 31, ty = threadIdx.x >> 5;     // 32 x 8
    for (int rr = ty; rr < 32; rr += 8)
        tile[rr][tx] = Wz[(long)(r0 + rr) * C + c0 + tx];
    __syncthreads();
    for (int rr = ty; rr < 32; rr += 8)
        Tz[(long)(c0 + rr) * R + r0 + tx] = f2bf(tile[tx][rr]);
}

// ---------------- patch im2col + hi/lo bf16 split: A row m = [xh|xh|xl] (768) ----
__global__ __launch_bounds__(256)
void k_split(const float* __restrict__ x, u16* __restrict__ A) {
    int m = blockIdx.x;               // 0..2047  (b*512 + n)
    int b = m >> 9, n = m & 511;
    int i = n >> 6, j = n & 63;       // patch grid 8 x 64
    int t = threadIdx.x;
    int pr = t >> 4, pc = t & 15;
    float v = x[(long)b * 131072 + (i * 16 + pr) * 1024 + j * 16 + pc];
    u16 hi = f2bf(v);
    u16 lo = f2bf(v - bf2f(hi));
    u16* row = A + (long)m * 768;
    row[t] = hi; row[256 + t] = hi; row[512 + t] = lo;
}

// ---------------- patch weight hi/lo split: Bt row d = [wh|wl|wh] (768) -------
__global__ __launch_bounds__(256)
void k_wsplit(const float* __restrict__ pw, u16* __restrict__ Bt) {
    int idx = blockIdx.x * 256 + threadIdx.x;   // over 384*256
    if (idx >= Dm * 256) return;
    int d = idx >> 8, k = idx & 255;
    float v = pw[idx];
    u16 hi = f2bf(v);
    u16 lo = f2bf(v - bf2f(hi));
    u16* row = Bt + (long)d * 768;
    row[k] = hi; row[256 + k] = lo; row[512 + k] = hi;
}

// ---------------- stable argsort of noise rows (512) via bitonic w/ index tie-break ----
__global__ __launch_bounds__(512)
void k_argsort(const float* __restrict__ noise, int* __restrict__ ids) {
    __shared__ float v[512];
    __shared__ int   ix[512];
    int b = blockIdx.x, t = threadIdx.x;
    v[t] = noise[b * 512 + t]; ix[t] = t;
    __syncthreads();
    for (int k = 2; k <= 512; k <<= 1)
        for (int j = k >> 1; j > 0; j >>= 1) {
            int p = t ^ j;
            if (p > t) {
                bool up = (t & k) == 0;
                float va = v[t], vb = v[p]; int ia = ix[t], ib = ix[p];
                bool sw = (va > vb) || (va == vb && ia > ib);
                if (sw == up) { v[t] = vb; v[p] = va; ix[t] = ib; ix[p] = ia; }
            }
            __syncthreads();
        }
    ids[b * 512 + t] = ix[t];
}

// ---------------- gather data tokens into xt rows [3..514], + pb + chan_table ----
__global__ void k_gather(const float* __restrict__ tmp, const int* __restrict__ ids,
                         const float* __restrict__ pb, const float* __restrict__ ctab,
                         const int* __restrict__ chan, float* __restrict__ xt) {
    long t = (long)blockIdx.x * 256 + threadIdx.x;
    if (t >= (long)Bq * NPATCH * Dm) return;
    int d = t % Dm; long r = t / Dm;
    int j = r % NPATCH, b = r / NPATCH;
    int src = ids[b * NPATCH + j];
    int ch = chan[b * NPATCH + src];
    xt[((long)b * LSEQ + NMETA + j) * Dm + d] =
        tmp[((long)b * NPATCH + src) * Dm + d] + pb[d] + ctab[(long)ch * Dm + d];
}

// ---------------- meta tokens, split-K stage 1: partial[g][c][d] --------------
// g = b(4) x mi(2) x part(2); c = K-chunk (32 x 125); d = 0..191
__global__ __launch_bounds__(192)
void k_meta1(const float* __restrict__ means, const float* __restrict__ stds,
             const float* __restrict__ mw, float* __restrict__ part) {
    int g = blockIdx.x, c = blockIdx.y;
    int d = threadIdx.x;
    int p = g & 1, mi = (g >> 1) & 1, b = g >> 2;
    const float* row = (p ? stds : means) + (long)(b * 2 + mi) * 4000 + c * KCH;
    const float* w = mw + (long)c * KCH * 192 + d;
    float a = 0.f;
    #pragma unroll 5
    for (int k = 0; k < KCH; k++) a += row[k] * w[(long)k * 192];
    part[((long)g * KSPL + c) * 192 + d] = a;
}

// ---------------- meta stage 2: reduce partials + bias -> xt rows 1,2 ---------
__global__ __launch_bounds__(192)
void k_meta2(const float* __restrict__ part, const float* __restrict__ mb,
             float* __restrict__ xt) {
    int g = blockIdx.x, d = threadIdx.x;
    int p = g & 1, mi = (g >> 1) & 1, b = g >> 2;
    float a = mb[d];
    #pragma unroll 8
    for (int c = 0; c < KSPL; c++) a += part[((long)g * KSPL + c) * 192 + d];
    xt[((long)b * LSEQ + 1 + mi) * Dm + p * 192 + d] = a;
}

// ---------------- cls row ----------------------------------------------------
__global__ void k_cls(const float* __restrict__ cls, float* __restrict__ xt) {
    int t = blockIdx.x * 256 + threadIdx.x;
    if (t >= Bq * Dm) return;
    int b = t / Dm, d = t % Dm;
    xt[(long)b * LSEQ * Dm + d] = cls[d];
}

// ---------------- meta_patches / mask / n_meta outputs -----------------------
__global__ void k_outextra(const float* __restrict__ xt, float* __restrict__ out) {
    int t = blockIdx.x * 256 + threadIdx.x;
    const int META = Bq * NMETA * Dm;          // 4608
    const int MASKN = Bq * NPATCH;             // 2048
    if (t < META) {
        int d = t % Dm; int r = t / Dm; int b = r / NMETA, mi = r % NMETA;
        out[791040 + t] = xt[((long)b * LSEQ + mi) * Dm + d];
    } else if (t < META + MASKN) {
        out[791040 + t] = 0.0f;                // mask (len_keep == 512)
    } else if (t == META + MASKN) {
        out[791040 + t] = 3.0f;                // n_meta
    }
}

// ---------------- RoPE cos/sin table -----------------------------------------
__global__ void k_ropetab(const int* __restrict__ win, float* __restrict__ ct,
                          float* __restrict__ st) {
    int t = blockIdx.x * 256 + threadIdx.x;
    if (t >= NPATCH * 32) return;
    int p = t & 31, n = t >> 5;
    int i = n >> 6, j = n & 63;
    float step = (float)(*win) * 0.25f / 0.125f;
    float inv, ang;
    if (p < 16) { inv = powf(100.0f, -(float)p / 16.0f);        ang = (float)j * step * inv; }
    else        { inv = powf(100.0f, -(float)(p - 16) / 16.0f); ang = (float)i * inv; }
    ct[t] = cosf(ang); st[t] = sinf(ang);
}

// ---------------- layernorm: 1 wave per row, D=384 ---------------------------
template<bool OUT_BF16>
__global__ __launch_bounds__(256)
void k_ln(const float* __restrict__ X, const float* __restrict__ g,
          const float* __restrict__ b, void* __restrict__ Y, int nrows) {
    int row = blockIdx.x * 4 + (threadIdx.x >> 6);
    if (row >= nrows) return;
    int lane = threadIdx.x & 63;
    const float* xr = X + (long)row * Dm;
    float v[6], s = 0.f;
    #pragma unroll
    for (int i = 0; i < 6; i++) { v[i] = xr[lane + 64 * i]; s += v[i]; }
    for (int off = 32; off; off >>= 1) s += __shfl_down(s, off);
    s = __shfl(s, 0);
    float mu = s / (float)Dm, vs = 0.f;
    #pragma unroll
    for (int i = 0; i < 6; i++) { float d = v[i] - mu; vs += d * d; }
    for (int off = 32; off; off >>= 1) vs += __shfl_down(vs, off);
    vs = __shfl(vs, 0);
    float rs = rsqrtf(vs / (float)Dm + 1e-6f);
    #pragma unroll
    for (int i = 0; i < 6; i++) {
        int c = lane + 64 * i;
        float o = (v[i] - mu) * rs * g[c] + b[c];
        if (OUT_BF16) ((u16*)Y)[(long)row * Dm + c] = f2bf(o);
        else          ((float*)Y)[(long)row * Dm + c] = o;
    }
}

// ---------------- rope apply + pack q/k/v to bf16 ----------------------------
// Qb, Kb: (B*H, 544, 64) row = token; Vt: (B*H, 64, 544) transposed
__global__ void k_ropepack(const float* __restrict__ qkv, const float* __restrict__ ct,
                           const float* __restrict__ st, u16* __restrict__ Qb,
                           u16* __restrict__ Kb, u16* __restrict__ Vt) {
    long tid = (long)blockIdx.x * 256 + threadIdx.x;   // over 24*544*32
    if (tid >= (long)24 * LPAD * 32) return;
    int p = tid & 31;
    long r = tid >> 5;
    int n = r % LPAD; long bh = r / LPAD;
    int b = bh / NHEADS, h = bh % NHEADS;
    float q0 = 0, q1 = 0, k0 = 0, k1 = 0, v0 = 0, v1 = 0;
    if (n < LSEQ) {
        const float* base = qkv + ((long)(b * LSEQ + n) * 1152 + h * HDh + 2 * p);
        q0 = base[0];   q1 = base[1];
        k0 = base[384]; k1 = base[385];
        v0 = base[768]; v1 = base[769];
        if (n >= NMETA) {
            int j = n - NMETA;
            float c = ct[j * 32 + p], s = st[j * 32 + p], a;
            a = q0 * c - q1 * s; q1 = q0 * s + q1 * c; q0 = a;
            a = k0 * c - k1 * s; k1 = k0 * s + k1 * c; k0 = a;
        }
    }
    long qo = (bh * LPAD + n) * (long)HDh + 2 * p;
    Qb[qo] = f2bf(q0); Qb[qo + 1] = f2bf(q1);
    Kb[qo] = f2bf(k0); Kb[qo + 1] = f2bf(k1);
    long vo = (bh * (long)HDh + 2 * p) * LPAD + n;
    Vt[vo] = f2bf(v0); Vt[vo + LPAD] = f2bf(v1);
}

// ---------------- softmax over S rows (scale folded in), write bf16 P --------
__global__ __launch_bounds__(256)
void k_softmax(const float* __restrict__ S, u16* __restrict__ P) {
    int row = blockIdx.x * 4 + (threadIdx.x >> 6);     // 0 .. 24*515-1
    if (row >= 24 * LSEQ) return;
    int lane = threadIdx.x & 63;
    const float* sr = S + (long)row * LPAD;
    float v[9], m = -1e30f;
    #pragma unroll
    for (int i = 0; i < 9; i++) {
        int c = lane + 64 * i;
        v[i] = (c < LSEQ) ? sr[c] * 0.125f : -1e30f;
        m = fmaxf(m, v[i]);
    }
    for (int off = 32; off; off >>= 1) m = fmaxf(m, __shfl_down(m, off));
    m = __shfl(m, 0);
    float sum = 0.f;
    #pragma unroll
    for (int i = 0; i < 9; i++) { v[i] = (v[i] > -1e29f) ? expf(v[i] - m) : 0.f; sum += v[i]; }
    for (int off = 32; off; off >>= 1) sum += __shfl_down(sum, off);
    sum = __shfl(sum, 0);
    float inv = 1.0f / sum;
    u16* pr = P + (long)row * LPAD;
    #pragma unroll
    for (int i = 0; i < 9; i++) {
        int c = lane + 64 * i;
        if (c < LPAD) pr[c] = f2bf((c < LSEQ) ? v[i] * inv : 0.0f);
    }
}

// ---------------- generic batched bf16 MFMA GEMM -----------------------------
// C[m][n] = epi( sum_k A[m][k] * Bt[n][k] + bias[n] )
// 64x64 block tile, BK=32, 4 waves (2x2), each wave 2x2 frags of 16x16x32.
template<int EPI>
__global__ __launch_bounds__(256)
void k_gemm(const u16* __restrict__ A, int lda, long sA, int M,
            const u16* __restrict__ Bt, int ldb, long sB, int btRows,
            void* __restrict__ Cptr, int ldc, long sCz1, long sCz2, int hdiv,
            const float* __restrict__ bias, const float* __restrict__ gamma,
            int N, int K) {
    __shared__ u16 Al[64][40];
    __shared__ u16 Bl[64][40];
    int z = blockIdx.z;
    const u16* Ab = A + (long)z * sA;
    const u16* Bb = Bt + (long)z * sB;
    long coff = (long)(z / hdiv) * sCz1 + (long)(z % hdiv) * sCz2;
    int row0 = blockIdx.x * 64, col0 = blockIdx.y * 64;
    int t = threadIdx.x;
    int lane = t & 63, w = t >> 6;
    int wr = (w >> 1) * 32, wc = (w & 1) * 32;
    int srow = t >> 2, skq = (t & 3) * 8;
    f32x4 acc[2][2] = {};
    for (int kk = 0; kk < K; kk += 32) {
        uint4 av = make_uint4(0, 0, 0, 0), bv = make_uint4(0, 0, 0, 0);
        if (row0 + srow < M)      av = *(const uint4*)(Ab + (long)(row0 + srow) * lda + kk + skq);
        if (col0 + srow < btRows) bv = *(const uint4*)(Bb + (long)(col0 + srow) * ldb + kk + skq);
        __syncthreads();
        *(uint4*)(&Al[srow][skq]) = av;
        *(uint4*)(&Bl[srow][skq]) = bv;
        __syncthreads();
        int fr = lane & 15, kg = (lane >> 4) * 8;
        bf16x8 af[2], bg[2];
        #pragma unroll
        for (int i = 0; i < 2; i++) {
            af[i] = *(const bf16x8*)(&Al[wr + 16 * i + fr][kg]);
            bg[i] = *(const bf16x8*)(&Bl[wc + 16 * i + fr][kg]);
        }
        #pragma unroll
        for (int mi = 0; mi < 2; mi++)
            #pragma unroll
            for (int nj = 0; nj < 2; nj++)
                acc[mi][nj] = __builtin_amdgcn_mfma_f32_16x16x32_bf16(af[mi], bg[nj], acc[mi][nj], 0, 0, 0);
    }
    int fr = lane & 15, rg = (lane >> 4) * 4;
    #pragma unroll
    for (int mi = 0; mi < 2; mi++)
        #pragma unroll
        for (int nj = 0; nj < 2; nj++)
            #pragma unroll
            for (int r = 0; r < 4; r++) {
                int row = row0 + wr + 16 * mi + rg + r;
                int col = col0 + wc + 16 * nj + fr;
                if (row >= M || col >= N) continue;
                float v = acc[mi][nj][r];
                if (bias) v += bias[col];
                long idx = coff + (long)row * ldc + col;
                if (EPI == EPI_F32)      ((float*)Cptr)[idx] = v;
                else if (EPI == EPI_BF16)((u16*)Cptr)[idx] = f2bf(v);
                else if (EPI == EPI_GELU) {
                    v = 0.5f * v * (1.0f + erff(v * 0.70710678118f));
                    ((u16*)Cptr)[idx] = f2bf(v);
                } else { // EPI_RES (in-place residual on f32 C)
                    float* C = (float*)Cptr;
                    C[idx] = C[idx] + gamma[col] * v;
                }
            }
}

// ---------------- host orchestration -----------------------------------------
extern "C" void kernel_launch(void* const* d_in, const int* in_sizes, int n_in,
                              void* d_out, int out_size, void* d_ws, size_t ws_size,
                              hipStream_t stream) {
    const float* x        = (const float*)d_in[0];
    const float* means    = (const float*)d_in[1];
    const float* stds     = (const float*)d_in[2];
    const int*   channels = (const int*)  d_in[3];
    const float* noise    = (const float*)d_in[4];
    const int*   win_size = (const int*)  d_in[5];
    // d_in[6] = mask_ratio (0)
    const float* patch_w  = (const float*)d_in[7];
    const float* patch_b  = (const float*)d_in[8];
    const float* cls_tok  = (const float*)d_in[9];
    const float* chan_tab = (const float*)d_in[10];
    const float* mean_w   = (const float*)d_in[11];
    const float* mean_b   = (const float*)d_in[12];
    const float* qkv_w    = (const float*)d_in[13];
    const float* qkv_b    = (const float*)d_in[14];
    const float* proj_w   = (const float*)d_in[15];
    const float* proj_b   = (const float*)d_in[16];
    const float* fc1_w    = (const float*)d_in[17];
    const float* fc1_b    = (const float*)d_in[18];
    const float* fc2_w    = (const float*)d_in[19];
    const float* fc2_b    = (const float*)d_in[20];
    const float* ln1_g    = (const float*)d_in[21];
    const float* ln1_b    = (const float*)d_in[22];
    const float* ln2_g    = (const float*)d_in[23];
    const float* ln2_b    = (const float*)d_in[24];
    const float* gamma1   = (const float*)d_in[25];
    const float* gamma2   = (const float*)d_in[26];
    const float* lnf_g    = (const float*)d_in[27];
    const float* lnf_b    = (const float*)d_in[28];
    float* out = (float*)d_out;

    char* wp = (char*)d_ws;
    auto alloc = [&](size_t bytes) { char* p = wp; wp += (bytes + 255) & ~(size_t)255; return p; };
    u16*   qkvT  = (u16*)  alloc((size_t)NDEPTH * 1152 * 384 * 2);
    u16*   projT = (u16*)  alloc((size_t)NDEPTH * 384 * 384 * 2);
    u16*   fc1T  = (u16*)  alloc((size_t)NDEPTH * 1536 * 384 * 2);
    u16*   fc2T  = (u16*)  alloc((size_t)NDEPTH * 384 * 1536 * 2);
    float* xt    = (float*)alloc((size_t)Bq * LSEQ * Dm * 4);
    u16*   yb    = (u16*)  alloc((size_t)Bq * LSEQ * Dm * 2);
    float* qkvb  = (float*)alloc((size_t)Bq * LSEQ * 1152 * 4);
    u16*   Qb    = (u16*)  alloc((size_t)24 * LPAD * HDh * 2);
    u16*   Kb    = (u16*)  alloc((size_t)24 * LPAD * HDh * 2);
    u16*   Vt    = (u16*)  alloc((size_t)24 * HDh * LPAD * 2);
    float* S     = (float*)alloc((size_t)24 * LSEQ * LPAD * 4);
    u16*   P     = (u16*)  alloc((size_t)24 * LSEQ * LPAD * 2);
    u16*   obuf  = (u16*)  alloc((size_t)Bq * LSEQ * Dm * 2);
    u16*   hid   = (u16*)  alloc((size_t)Bq * LSEQ * 1536 * 2);
    float* tmp   = (float*)alloc((size_t)Bq * NPATCH * Dm * 4);
    float* ct    = (float*)alloc((size_t)NPATCH * 32 * 4);
    float* st    = (float*)alloc((size_t)NPATCH * 32 * 4);
    int*   ids   = (int*)  alloc((size_t)Bq * NPATCH * 4);
    float* mpart = (float*)alloc((size_t)16 * KSPL * 192 * 4);
    u16*   Axl   = (u16*)  alloc((size_t)Bq * NPATCH * 768 * 2);
    u16*   Bw    = (u16*)  alloc((size_t)Dm * 768 * 2);

    // weights -> bf16 transposed
    k_transpose<<<dim3(1152 / 32, 384 / 32, NDEPTH), 256, 0, stream>>>(qkv_w, qkvT, 384, 1152);
    k_transpose<<<dim3(384 / 32, 384 / 32, NDEPTH), 256, 0, stream>>>(proj_w, projT, 384, 384);
    k_transpose<<<dim3(1536 / 32, 384 / 32, NDEPTH), 256, 0, stream>>>(fc1_w, fc1T, 384, 1536);
    k_transpose<<<dim3(384 / 32, 1536 / 32, NDEPTH), 256, 0, stream>>>(fc2_w, fc2T, 1536, 384);

    // patch embed as hi/lo bf16 MFMA GEMM: tmp[m][d] = patch(m) . pw(d)
    k_split<<<Bq * NPATCH, 256, 0, stream>>>(x, Axl);
    k_wsplit<<<(Dm * 256 + 255) / 256, 256, 0, stream>>>(patch_w, Bw);
    k_gemm<EPI_F32><<<dim3(Bq * NPATCH / 64, Dm / 64, 1), 256, 0, stream>>>(
        Axl, 768, 0, Bq * NPATCH,
        Bw, 768, 0, Dm,
        tmp, Dm, 0, 0, 1,
        nullptr, nullptr, Dm, 768);

    // build initial xt
    k_argsort<<<Bq, 512, 0, stream>>>(noise, ids);
    k_gather<<<(Bq * NPATCH * Dm + 255) / 256, 256, 0, stream>>>(tmp, ids, patch_b, chan_tab, channels, xt);
    k_meta1<<<dim3(16, KSPL), 192, 0, stream>>>(means, stds, mean_w, mpart);
    k_meta2<<<16, 192, 0, stream>>>(mpart, mean_b, xt);
    k_cls<<<(Bq * Dm + 255) / 256, 256, 0, stream>>>(cls_tok, xt);
    k_outextra<<<(4608 + 2048 + 1 + 255) / 256, 256, 0, stream>>>(xt, out);
    k_ropetab<<<(NPATCH * 32 + 255) / 256, 256, 0, stream>>>(win_size, ct, st);

    const int ROWS = Bq * LSEQ;        // 2060
    const int MT = (ROWS + 63) / 64;   // 33
    const int NT_S = (LPAD + 63) / 64; // 9
    for (int d = 0; d < NDEPTH; d++) {
        k_ln<true><<<(ROWS + 3) / 4, 256, 0, stream>>>(xt, ln1_g + d * Dm, ln1_b + d * Dm, yb, ROWS);
        // qkv: (2060 x 384) @ (384 x 1152) + b -> f32
        k_gemm<EPI_F32><<<dim3(MT, 1152 / 64, 1), 256, 0, stream>>>(
            yb, Dm, 0, ROWS,
            qkvT + (long)d * 1152 * 384, 384, 0, 1152,
            qkvb, 1152, 0, 0, 1,
            qkv_b + d * 1152, nullptr, 1152, 384);
        k_ropepack<<<(24 * LPAD * 32 + 255) / 256, 256, 0, stream>>>(qkvb, ct, st, Qb, Kb, Vt);
        // S = Q @ K^T : batched 24, M=515, N=544(padded), K=64
        k_gemm<EPI_F32><<<dim3((LSEQ + 63) / 64, NT_S, 24), 256, 0, stream>>>(
            Qb, HDh, (long)LPAD * HDh, LSEQ,
            Kb, HDh, (long)LPAD * HDh, LPAD,
            S, LPAD, (long)LSEQ * LPAD, 0, 1,
            nullptr, nullptr, LPAD, HDh);
        k_softmax<<<(24 * LSEQ + 3) / 4, 256, 0, stream>>>(S, P);
        // O = P @ V : batched 24, M=515, N=64, K=544 -> obuf (B, L, 384) bf16
        k_gemm<EPI_BF16><<<dim3((LSEQ + 63) / 64, 1, 24), 256, 0, stream>>>(
            P, LPAD, (long)LSEQ * LPAD, LSEQ,
            Vt, LPAD, (long)HDh * LPAD, HDh,
            obuf, Dm, (long)LSEQ * Dm, HDh, NHEADS,
            nullptr, nullptr, HDh, LPAD);
        // proj + gamma1 residual into xt
        k_gemm<EPI_RES><<<dim3(MT, Dm / 64, 1), 256, 0, stream>>>(
            obuf, Dm, 0, ROWS,
            projT + (long)d * 384 * 384, 384, 0, 384,
            xt, Dm, 0, 0, 1,
            proj_b + d * Dm, gamma1 + d * Dm, Dm, 384);
        k_ln<true><<<(ROWS + 3) / 4, 256, 0, stream>>>(xt, ln2_g + d * Dm, ln2_b + d * Dm, yb, ROWS);
        // fc1 + gelu -> hid bf16
        k_gemm<EPI_GELU><<<dim3(MT, 1536 / 64, 1), 256, 0, stream>>>(
            yb, Dm, 0, ROWS,
            fc1T + (long)d * 1536 * 384, 384, 0, 1536,
            hid, 1536, 0, 0, 1,
            fc1_b + d * 1536, nullptr, 1536, 384);
        // fc2 + gamma2 residual into xt
        k_gemm<EPI_RES><<<dim3(MT, Dm / 64, 1), 256, 0, stream>>>(
            hid, 1536, 0, ROWS,
            fc2T + (long)d * 384 * 1536, 1536, 0, 384,
            xt, Dm, 0, 0, 1,
            fc2_b + d * Dm, gamma2 + d * Dm, Dm, 1536);
    }
    // final layernorm -> d_out (f32)
    k_ln<false><<<(ROWS + 3) / 4, 256, 0, stream>>>(xt, lnf_g, lnf_b, out, ROWS);
}

// Round 10
// 1458.963 us; speedup vs baseline: 1.3827x; 1.1069x over previous
//
#include <hip/hip_runtime.h>
#include <hip/hip_bf16.h>
#include <math.h>

// ---------------- constants ----------------
#define Bq     4
#define LSEQ   515          // 3 meta + 512 data tokens
#define NMETA  3
#define NPATCH 512
#define Dm     384
#define NHEADS 6
#define HDh    64
#define NDEPTH 12
#define LPAD   544          // 515 padded to multiple of 32
#define KSPL   32           // split-K chunks for meta GEMM
#define KCH    125          // 4000 / KSPL

typedef unsigned short u16;
typedef short bf16x8 __attribute__((ext_vector_type(8)));
typedef float f32x4  __attribute__((ext_vector_type(4)));

enum { EPI_F32 = 0, EPI_BF16 = 1, EPI_GELU = 2, EPI_RES = 3 };

__device__ inline u16 f2bf(float x) {
    __hip_bfloat16 h = __float2bfloat16(x);
    return *reinterpret_cast<u16*>(&h);
}
__device__ inline float bf2f(u16 x) {
    __hip_bfloat16 h = *reinterpret_cast<__hip_bfloat16*>(&x);
    return __bfloat162float(h);
}

// ---------------- weight transpose + cast: W (R x C) f32 -> WT (C x R) bf16, per layer z ----
__global__ __launch_bounds__(256)
void k_transpose(const float* __restrict__ W, u16* __restrict__ WT, int R, int C) {
    __shared__ float tile[32][33];
    int z = blockIdx.z;
    const float* Wz = W + (long)z * R * C;
    u16* Tz = WT + (long)z * R * C;
    int c0 = blockIdx.x * 32, r0 = blockIdx.y * 32;
    int tx = threadIdx.x & 31, ty = threadIdx.x >> 5;     // 32 x 8
    for (int rr = ty; rr < 32; rr += 8)
        tile[rr][tx] = Wz[(long)(r0 + rr) * C + c0 + tx];
    __syncthreads();
    for (int rr = ty; rr < 32; rr += 8)
        Tz[(long)(c0 + rr) * R + r0 + tx] = f2bf(tile[tx][rr]);
}

// ---------------- patch im2col + hi/lo bf16 split: A row m = [xh|xh|xl] (768) ----
__global__ __launch_bounds__(256)
void k_split(const float* __restrict__ x, u16* __restrict__ A) {
    int m = blockIdx.x;               // 0..2047  (b*512 + n)
    int b = m >> 9, n = m & 511;
    int i = n >> 6, j = n & 63;       // patch grid 8 x 64
    int t = threadIdx.x;
    int pr = t >> 4, pc = t & 15;
    float v = x[(long)b * 131072 + (i * 16 + pr) * 1024 + j * 16 + pc];
    u16 hi = f2bf(v);
    u16 lo = f2bf(v - bf2f(hi));
    u16* row = A + (long)m * 768;
    row[t] = hi; row[256 + t] = hi; row[512 + t] = lo;
}

// ---------------- patch weight hi/lo split: Bt row d = [wh|wl|wh] (768) -------
__global__ __launch_bounds__(256)
void k_wsplit(const float* __restrict__ pw, u16* __restrict__ Bt) {
    int idx = blockIdx.x * 256 + threadIdx.x;   // over 384*256
    if (idx >= Dm * 256) return;
    int d = idx >> 8, k = idx & 255;
    float v = pw[idx];
    u16 hi = f2bf(v);
    u16 lo = f2bf(v - bf2f(hi));
    u16* row = Bt + (long)d * 768;
    row[k] = hi; row[256 + k] = lo; row[512 + k] = hi;
}

// ---------------- stable argsort of noise rows (512) via bitonic w/ index tie-break ----
__global__ __launch_bounds__(512)
void k_argsort(const float* __restrict__ noise, int* __restrict__ ids) {
    __shared__ float v[512];
    __shared__ int   ix[512];
    int b = blockIdx.x, t = threadIdx.x;
    v[t] = noise[b * 512 + t]; ix[t] = t;
    __syncthreads();
    for (int k = 2; k <= 512; k <<= 1)
        for (int j = k >> 1; j > 0; j >>= 1) {
            int p = t ^ j;
            if (p > t) {
                bool up = (t & k) == 0;
                float va = v[t], vb = v[p]; int ia = ix[t], ib = ix[p];
                bool sw = (va > vb) || (va == vb && ia > ib);
                if (sw == up) { v[t] = vb; v[p] = va; ix[t] = ib; ix[p] = ia; }
            }
            __syncthreads();
        }
    ids[b * 512 + t] = ix[t];
}

// ---------------- gather data tokens into xt rows [3..514], + pb + chan_table ----
__global__ void k_gather(const float* __restrict__ tmp, const int* __restrict__ ids,
                         const float* __restrict__ pb, const float* __restrict__ ctab,
                         const int* __restrict__ chan, float* __restrict__ xt) {
    long t = (long)blockIdx.x * 256 + threadIdx.x;
    if (t >= (long)Bq * NPATCH * Dm) return;
    int d = t % Dm; long r = t / Dm;
    int j = r % NPATCH, b = r / NPATCH;
    int src = ids[b * NPATCH + j];
    int ch = chan[b * NPATCH + src];
    xt[((long)b * LSEQ + NMETA + j) * Dm + d] =
        tmp[((long)b * NPATCH + src) * Dm + d] + pb[d] + ctab[(long)ch * Dm + d];
}

// ---------------- meta tokens, split-K stage 1: partial[g][c][d] --------------
__global__ __launch_bounds__(192)
void k_meta1(const float* __restrict__ means, const float* __restrict__ stds,
             const float* __restrict__ mw, float* __restrict__ part) {
    int g = blockIdx.x, c = blockIdx.y;
    int d = threadIdx.x;
    int p = g & 1, mi = (g >> 1) & 1, b = g >> 2;
    const float* row = (p ? stds : means) + (long)(b * 2 + mi) * 4000 + c * KCH;
    const float* w = mw + (long)c * KCH * 192 + d;
    float a = 0.f;
    #pragma unroll 5
    for (int k = 0; k < KCH; k++) a += row[k] * w[(long)k * 192];
    part[((long)g * KSPL + c) * 192 + d] = a;
}

// ---------------- meta stage 2: reduce partials + bias -> xt rows 1,2 ---------
__global__ __launch_bounds__(192)
void k_meta2(const float* __restrict__ part, const float* __restrict__ mb,
             float* __restrict__ xt) {
    int g = blockIdx.x, d = threadIdx.x;
    int p = g & 1, mi = (g >> 1) & 1, b = g >> 2;
    float a = mb[d];
    #pragma unroll 8
    for (int c = 0; c < KSPL; c++) a += part[((long)g * KSPL + c) * 192 + d];
    xt[((long)b * LSEQ + 1 + mi) * Dm + p * 192 + d] = a;
}

// ---------------- cls row ----------------------------------------------------
__global__ void k_cls(const float* __restrict__ cls, float* __restrict__ xt) {
    int t = blockIdx.x * 256 + threadIdx.x;
    if (t >= Bq * Dm) return;
    int b = t / Dm, d = t % Dm;
    xt[(long)b * LSEQ * Dm + d] = cls[d];
}

// ---------------- meta_patches / mask / n_meta outputs -----------------------
__global__ void k_outextra(const float* __restrict__ xt, float* __restrict__ out) {
    int t = blockIdx.x * 256 + threadIdx.x;
    const int META = Bq * NMETA * Dm;          // 4608
    const int MASKN = Bq * NPATCH;             // 2048
    if (t < META) {
        int d = t % Dm; int r = t / Dm; int b = r / NMETA, mi = r % NMETA;
        out[791040 + t] = xt[((long)b * LSEQ + mi) * Dm + d];
    } else if (t < META + MASKN) {
        out[791040 + t] = 0.0f;                // mask (len_keep == 512)
    } else if (t == META + MASKN) {
        out[791040 + t] = 3.0f;                // n_meta
    }
}

// ---------------- RoPE cos/sin table -----------------------------------------
__global__ void k_ropetab(const int* __restrict__ win, float* __restrict__ ct,
                          float* __restrict__ st) {
    int t = blockIdx.x * 256 + threadIdx.x;
    if (t >= NPATCH * 32) return;
    int p = t & 31, n = t >> 5;
    int i = n >> 6, j = n & 63;
    float step = (float)(*win) * 0.25f / 0.125f;
    float inv, ang;
    if (p < 16) { inv = powf(100.0f, -(float)p / 16.0f);        ang = (float)j * step * inv; }
    else        { inv = powf(100.0f, -(float)(p - 16) / 16.0f); ang = (float)i * inv; }
    ct[t] = cosf(ang); st[t] = sinf(ang);
}

// ---------------- layernorm: 1 wave per row, D=384 ---------------------------
template<bool OUT_BF16>
__global__ __launch_bounds__(256)
void k_ln(const float* __restrict__ X, const float* __restrict__ g,
          const float* __restrict__ b, void* __restrict__ Y, int nrows) {
    int row = blockIdx.x * 4 + (threadIdx.x >> 6);
    if (row >= nrows) return;
    int lane = threadIdx.x & 63;
    const float* xr = X + (long)row * Dm;
    float v[6], s = 0.f;
    #pragma unroll
    for (int i = 0; i < 6; i++) { v[i] = xr[lane + 64 * i]; s += v[i]; }
    for (int off = 32; off; off >>= 1) s += __shfl_down(s, off);
    s = __shfl(s, 0);
    float mu = s / (float)Dm, vs = 0.f;
    #pragma unroll
    for (int i = 0; i < 6; i++) { float d = v[i] - mu; vs += d * d; }
    for (int off = 32; off; off >>= 1) vs += __shfl_down(vs, off);
    vs = __shfl(vs, 0);
    float rs = rsqrtf(vs / (float)Dm + 1e-6f);
    #pragma unroll
    for (int i = 0; i < 6; i++) {
        int c = lane + 64 * i;
        float o = (v[i] - mu) * rs * g[c] + b[c];
        if (OUT_BF16) ((u16*)Y)[(long)row * Dm + c] = f2bf(o);
        else          ((float*)Y)[(long)row * Dm + c] = o;
    }
}

// ---------------- rope apply + pack q/k/v to bf16 ----------------------------
// Qb, Kb: (B*H, 544, 64) row = token; Vt: (B*H, 64, 544) transposed
__global__ void k_ropepack(const float* __restrict__ qkv, const float* __restrict__ ct,
                           const float* __restrict__ st, u16* __restrict__ Qb,
                           u16* __restrict__ Kb, u16* __restrict__ Vt) {
    long tid = (long)blockIdx.x * 256 + threadIdx.x;   // over 24*544*32
    if (tid >= (long)24 * LPAD * 32) return;
    int p = tid & 31;
    long r = tid >> 5;
    int n = r % LPAD; long bh = r / LPAD;
    int b = bh / NHEADS, h = bh % NHEADS;
    float q0 = 0, q1 = 0, k0 = 0, k1 = 0, v0 = 0, v1 = 0;
    if (n < LSEQ) {
        const float* base = qkv + ((long)(b * LSEQ + n) * 1152 + h * HDh + 2 * p);
        q0 = base[0];   q1 = base[1];
        k0 = base[384]; k1 = base[385];
        v0 = base[768]; v1 = base[769];
        if (n >= NMETA) {
            int j = n - NMETA;
            float c = ct[j * 32 + p], s = st[j * 32 + p], a;
            a = q0 * c - q1 * s; q1 = q0 * s + q1 * c; q0 = a;
            a = k0 * c - k1 * s; k1 = k0 * s + k1 * c; k0 = a;
        }
    }
    long qo = (bh * LPAD + n) * (long)HDh + 2 * p;
    Qb[qo] = f2bf(q0); Qb[qo + 1] = f2bf(q1);
    Kb[qo] = f2bf(k0); Kb[qo + 1] = f2bf(k1);
    long vo = (bh * (long)HDh + 2 * p) * LPAD + n;
    Vt[vo] = f2bf(v0); Vt[vo + LPAD] = f2bf(v1);
}

// ---------------- fused flash attention ---------------------------------------
// grid (9 q-tiles, 24 bh); 4 waves; wave w owns q rows [q0+16w, q0+16w+16),
// all 64 tokens of the staged K/V tile. Online softmax in registers.
__global__ __launch_bounds__(256)
void k_flash(const u16* __restrict__ Qb, const u16* __restrict__ Kb,
             const u16* __restrict__ Vt, u16* __restrict__ obuf) {
    __shared__ u16 Ql[64][72];
    __shared__ u16 Kl[64][72];
    __shared__ u16 Vl[64][72];       // Vl[d][tok]
    __shared__ u16 Pl[4][16][72];    // wave-private P relayout
    int bh = blockIdx.y;
    int b = bh / NHEADS, h = bh % NHEADS;
    int q0 = blockIdx.x * 64;
    int t = threadIdx.x, lane = t & 63, w = t >> 6;
    int srow = t >> 2, scol = (t & 3) * 16;
    int fr = lane & 15, kq = lane >> 4;
    const uint4 z4 = make_uint4(0, 0, 0, 0);

    // stage Q tile (rows beyond LPAD -> 0; rows 515..543 already 0 in Qb)
    {
        uint4 v0 = z4, v1 = z4;
        if (q0 + srow < LPAD) {
            const u16* p = Qb + ((long)bh * LPAD + q0 + srow) * HDh + scol;
            v0 = *(const uint4*)p; v1 = *(const uint4*)(p + 8);
        }
        *(uint4*)&Ql[srow][scol] = v0;
        *(uint4*)&Ql[srow][scol + 8] = v1;
    }

    float m_r[4], l_r[4];
    #pragma unroll
    for (int r = 0; r < 4; r++) { m_r[r] = -1e30f; l_r[r] = 0.f; }
    f32x4 Of[4] = {};

    for (int kt = 0; kt < 9; kt++) {
        int kv0 = kt * 64;
        // issue global loads for K/V tile
        uint4 kv0r = z4, kv1r = z4, vv0 = z4, vv1 = z4;
        if (kv0 + srow < LPAD) {
            const u16* p = Kb + ((long)bh * LPAD + kv0 + srow) * HDh + scol;
            kv0r = *(const uint4*)p; kv1r = *(const uint4*)(p + 8);
        }
        if (kv0 + scol < LPAD) {     // 16-col chunks: fully valid or fully OOB
            const u16* pv = Vt + ((long)bh * HDh + srow) * LPAD + kv0 + scol;
            vv0 = *(const uint4*)pv; vv1 = *(const uint4*)(pv + 8);
        }
        __syncthreads();             // previous iteration's LDS reads done
        *(uint4*)&Kl[srow][scol] = kv0r;
        *(uint4*)&Kl[srow][scol + 8] = kv1r;
        *(uint4*)&Vl[srow][scol] = vv0;
        *(uint4*)&Vl[srow][scol + 8] = vv1;
        __syncthreads();

        // S = Q K^T for this wave's 16 q rows x 64 tokens
        f32x4 sa[4] = {};
        #pragma unroll
        for (int ks = 0; ks < 2; ks++) {
            bf16x8 af = *(const bf16x8*)&Ql[w * 16 + fr][ks * 32 + kq * 8];
            #pragma unroll
            for (int nj = 0; nj < 4; nj++) {
                bf16x8 bg = *(const bf16x8*)&Kl[nj * 16 + fr][ks * 32 + kq * 8];
                sa[nj] = __builtin_amdgcn_mfma_f32_16x16x32_bf16(af, bg, sa[nj], 0, 0, 0);
            }
        }
        // mask + scale, row max
        float rm[4], rs[4];
        #pragma unroll
        for (int r = 0; r < 4; r++) rm[r] = -1e30f;
        #pragma unroll
        for (int nj = 0; nj < 4; nj++) {
            bool valid = (kv0 + nj * 16 + fr) < LSEQ;
            #pragma unroll
            for (int r = 0; r < 4; r++) {
                float s = valid ? sa[nj][r] * 0.125f : -1e30f;
                sa[nj][r] = s;
                rm[r] = fmaxf(rm[r], s);
            }
        }
        #pragma unroll
        for (int r = 0; r < 4; r++) {
            #pragma unroll
            for (int off = 1; off < 16; off <<= 1)
                rm[r] = fmaxf(rm[r], __shfl_xor(rm[r], off));
        }
        float sc[4];
        #pragma unroll
        for (int r = 0; r < 4; r++) {
            float mn = fmaxf(m_r[r], rm[r]);
            sc[r] = __expf(m_r[r] - mn);
            m_r[r] = mn;
            rs[r] = 0.f;
        }
        #pragma unroll
        for (int nj = 0; nj < 4; nj++)
            #pragma unroll
            for (int r = 0; r < 4; r++) {
                float p = __expf(sa[nj][r] - m_r[r]);   // masked -> 0
                sa[nj][r] = p;
                rs[r] += p;
            }
        #pragma unroll
        for (int r = 0; r < 4; r++) {
            #pragma unroll
            for (int off = 1; off < 16; off <<= 1)
                rs[r] += __shfl_xor(rs[r], off);
            l_r[r] = l_r[r] * sc[r] + rs[r];
        }
        // P: C-layout regs -> wave-private LDS -> A-frag layout
        #pragma unroll
        for (int nj = 0; nj < 4; nj++)
            #pragma unroll
            for (int r = 0; r < 4; r++)
                Pl[w][kq * 4 + r][nj * 16 + fr] = f2bf(sa[nj][r]);
        bf16x8 pa0 = *(const bf16x8*)&Pl[w][fr][kq * 8];
        bf16x8 pa1 = *(const bf16x8*)&Pl[w][fr][32 + kq * 8];
        // rescale O, accumulate P V
        #pragma unroll
        for (int nd = 0; nd < 4; nd++)
            #pragma unroll
            for (int r = 0; r < 4; r++) Of[nd][r] *= sc[r];
        #pragma unroll
        for (int nd = 0; nd < 4; nd++) {
            bf16x8 bg0 = *(const bf16x8*)&Vl[nd * 16 + fr][kq * 8];
            bf16x8 bg1 = *(const bf16x8*)&Vl[nd * 16 + fr][32 + kq * 8];
            Of[nd] = __builtin_amdgcn_mfma_f32_16x16x32_bf16(pa0, bg0, Of[nd], 0, 0, 0);
            Of[nd] = __builtin_amdgcn_mfma_f32_16x16x32_bf16(pa1, bg1, Of[nd], 0, 0, 0);
        }
    }
    // normalize + store
    #pragma unroll
    for (int r = 0; r < 4; r++) {
        int q = q0 + w * 16 + kq * 4 + r;
        if (q >= LSEQ) continue;
        float inv = 1.0f / l_r[r];
        #pragma unroll
        for (int nd = 0; nd < 4; nd++)
            obuf[((long)b * LSEQ + q) * Dm + h * HDh + nd * 16 + fr] = f2bf(Of[nd][r] * inv);
    }
}

// ---------------- generic batched bf16 MFMA GEMM -----------------------------
template<int EPI>
__global__ __launch_bounds__(256)
void k_gemm(const u16* __restrict__ A, int lda, long sA, int M,
            const u16* __restrict__ Bt, int ldb, long sB, int btRows,
            void* __restrict__ Cptr, int ldc, long sCz1, long sCz2, int hdiv,
            const float* __restrict__ bias, const float* __restrict__ gamma,
            int N, int K) {
    __shared__ u16 Al[64][40];
    __shared__ u16 Bl[64][40];
    int z = blockIdx.z;
    const u16* Ab = A + (long)z * sA;
    const u16* Bb = Bt + (long)z * sB;
    long coff = (long)(z / hdiv) * sCz1 + (long)(z % hdiv) * sCz2;
    int row0 = blockIdx.x * 64, col0 = blockIdx.y * 64;
    int t = threadIdx.x;
    int lane = t & 63, w = t >> 6;
    int wr = (w >> 1) * 32, wc = (w & 1) * 32;
    int srow = t >> 2, skq = (t & 3) * 8;
    f32x4 acc[2][2] = {};
    for (int kk = 0; kk < K; kk += 32) {
        uint4 av = make_uint4(0, 0, 0, 0), bv = make_uint4(0, 0, 0, 0);
        if (row0 + srow < M)      av = *(const uint4*)(Ab + (long)(row0 + srow) * lda + kk + skq);
        if (col0 + srow < btRows) bv = *(const uint4*)(Bb + (long)(col0 + srow) * ldb + kk + skq);
        __syncthreads();
        *(uint4*)(&Al[srow][skq]) = av;
        *(uint4*)(&Bl[srow][skq]) = bv;
        __syncthreads();
        int fr = lane & 15, kg = (lane >> 4) * 8;
        bf16x8 af[2], bg[2];
        #pragma unroll
        for (int i = 0; i < 2; i++) {
            af[i] = *(const bf16x8*)(&Al[wr + 16 * i + fr][kg]);
            bg[i] = *(const bf16x8*)(&Bl[wc + 16 * i + fr][kg]);
        }
        #pragma unroll
        for (int mi = 0; mi < 2; mi++)
            #pragma unroll
            for (int nj = 0; nj < 2; nj++)
                acc[mi][nj] = __builtin_amdgcn_mfma_f32_16x16x32_bf16(af[mi], bg[nj], acc[mi][nj], 0, 0, 0);
    }
    int fr = lane & 15, rg = (lane >> 4) * 4;
    #pragma unroll
    for (int mi = 0; mi < 2; mi++)
        #pragma unroll
        for (int nj = 0; nj < 2; nj++)
            #pragma unroll
            for (int r = 0; r < 4; r++) {
                int row = row0 + wr + 16 * mi + rg + r;
                int col = col0 + wc + 16 * nj + fr;
                if (row >= M || col >= N) continue;
                float v = acc[mi][nj][r];
                if (bias) v += bias[col];
                long idx = coff + (long)row * ldc + col;
                if (EPI == EPI_F32)      ((float*)Cptr)[idx] = v;
                else if (EPI == EPI_BF16)((u16*)Cptr)[idx] = f2bf(v);
                else if (EPI == EPI_GELU) {
                    v = 0.5f * v * (1.0f + erff(v * 0.70710678118f));
                    ((u16*)Cptr)[idx] = f2bf(v);
                } else { // EPI_RES (in-place residual on f32 C)
                    float* C = (float*)Cptr;
                    C[idx] = C[idx] + gamma[col] * v;
                }
            }
}

// ---------------- host orchestration -----------------------------------------
extern "C" void kernel_launch(void* const* d_in, const int* in_sizes, int n_in,
                              void* d_out, int out_size, void* d_ws, size_t ws_size,
                              hipStream_t stream) {
    const float* x        = (const float*)d_in[0];
    const float* means    = (const float*)d_in[1];
    const float* stds     = (const float*)d_in[2];
    const int*   channels = (const int*)  d_in[3];
    const float* noise    = (const float*)d_in[4];
    const int*   win_size = (const int*)  d_in[5];
    // d_in[6] = mask_ratio (0)
    const float* patch_w  = (const float*)d_in[7];
    const float* patch_b  = (const float*)d_in[8];
    const float* cls_tok  = (const float*)d_in[9];
    const float* chan_tab = (const float*)d_in[10];
    const float* mean_w   = (const float*)d_in[11];
    const float* mean_b   = (const float*)d_in[12];
    const float* qkv_w    = (const float*)d_in[13];
    const float* qkv_b    = (const float*)d_in[14];
    const float* proj_w   = (const float*)d_in[15];
    const float* proj_b   = (const float*)d_in[16];
    const float* fc1_w    = (const float*)d_in[17];
    const float* fc1_b    = (const float*)d_in[18];
    const float* fc2_w    = (const float*)d_in[19];
    const float* fc2_b    = (const float*)d_in[20];
    const float* ln1_g    = (const float*)d_in[21];
    const float* ln1_b    = (const float*)d_in[22];
    const float* ln2_g    = (const float*)d_in[23];
    const float* ln2_b    = (const float*)d_in[24];
    const float* gamma1   = (const float*)d_in[25];
    const float* gamma2   = (const float*)d_in[26];
    const float* lnf_g    = (const float*)d_in[27];
    const float* lnf_b    = (const float*)d_in[28];
    float* out = (float*)d_out;

    char* wp = (char*)d_ws;
    auto alloc = [&](size_t bytes) { char* p = wp; wp += (bytes + 255) & ~(size_t)255; return p; };
    u16*   qkvT  = (u16*)  alloc((size_t)NDEPTH * 1152 * 384 * 2);
    u16*   projT = (u16*)  alloc((size_t)NDEPTH * 384 * 384 * 2);
    u16*   fc1T  = (u16*)  alloc((size_t)NDEPTH * 1536 * 384 * 2);
    u16*   fc2T  = (u16*)  alloc((size_t)NDEPTH * 384 * 1536 * 2);
    float* xt    = (float*)alloc((size_t)Bq * LSEQ * Dm * 4);
    u16*   yb    = (u16*)  alloc((size_t)Bq * LSEQ * Dm * 2);
    float* qkvb  = (float*)alloc((size_t)Bq * LSEQ * 1152 * 4);
    u16*   Qb    = (u16*)  alloc((size_t)24 * LPAD * HDh * 2);
    u16*   Kb    = (u16*)  alloc((size_t)24 * LPAD * HDh * 2);
    u16*   Vt    = (u16*)  alloc((size_t)24 * HDh * LPAD * 2);
    u16*   obuf  = (u16*)  alloc((size_t)Bq * LSEQ * Dm * 2);
    u16*   hid   = (u16*)  alloc((size_t)Bq * LSEQ * 1536 * 2);
    float* tmp   = (float*)alloc((size_t)Bq * NPATCH * Dm * 4);
    float* ct    = (float*)alloc((size_t)NPATCH * 32 * 4);
    float* st    = (float*)alloc((size_t)NPATCH * 32 * 4);
    int*   ids   = (int*)  alloc((size_t)Bq * NPATCH * 4);
    float* mpart = (float*)alloc((size_t)16 * KSPL * 192 * 4);
    u16*   Axl   = (u16*)  alloc((size_t)Bq * NPATCH * 768 * 2);
    u16*   Bw    = (u16*)  alloc((size_t)Dm * 768 * 2);

    // weights -> bf16 transposed
    k_transpose<<<dim3(1152 / 32, 384 / 32, NDEPTH), 256, 0, stream>>>(qkv_w, qkvT, 384, 1152);
    k_transpose<<<dim3(384 / 32, 384 / 32, NDEPTH), 256, 0, stream>>>(proj_w, projT, 384, 384);
    k_transpose<<<dim3(1536 / 32, 384 / 32, NDEPTH), 256, 0, stream>>>(fc1_w, fc1T, 384, 1536);
    k_transpose<<<dim3(384 / 32, 1536 / 32, NDEPTH), 256, 0, stream>>>(fc2_w, fc2T, 1536, 384);

    // patch embed as hi/lo bf16 MFMA GEMM: tmp[m][d] = patch(m) . pw(d)
    k_split<<<Bq * NPATCH, 256, 0, stream>>>(x, Axl);
    k_wsplit<<<(Dm * 256 + 255) / 256, 256, 0, stream>>>(patch_w, Bw);
    k_gemm<EPI_F32><<<dim3(Bq * NPATCH / 64, Dm / 64, 1), 256, 0, stream>>>(
        Axl, 768, 0, Bq * NPATCH,
        Bw, 768, 0, Dm,
        tmp, Dm, 0, 0, 1,
        nullptr, nullptr, Dm, 768);

    // build initial xt
    k_argsort<<<Bq, 512, 0, stream>>>(noise, ids);
    k_gather<<<(Bq * NPATCH * Dm + 255) / 256, 256, 0, stream>>>(tmp, ids, patch_b, chan_tab, channels, xt);
    k_meta1<<<dim3(16, KSPL), 192, 0, stream>>>(means, stds, mean_w, mpart);
    k_meta2<<<16, 192, 0, stream>>>(mpart, mean_b, xt);
    k_cls<<<(Bq * Dm + 255) / 256, 256, 0, stream>>>(cls_tok, xt);
    k_outextra<<<(4608 + 2048 + 1 + 255) / 256, 256, 0, stream>>>(xt, out);
    k_ropetab<<<(NPATCH * 32 + 255) / 256, 256, 0, stream>>>(win_size, ct, st);

    const int ROWS = Bq * LSEQ;        // 2060
    const int MT = (ROWS + 63) / 64;   // 33
    for (int d = 0; d < NDEPTH; d++) {
        k_ln<true><<<(ROWS + 3) / 4, 256, 0, stream>>>(xt, ln1_g + d * Dm, ln1_b + d * Dm, yb, ROWS);
        // qkv: (2060 x 384) @ (384 x 1152) + b -> f32
        k_gemm<EPI_F32><<<dim3(MT, 1152 / 64, 1), 256, 0, stream>>>(
            yb, Dm, 0, ROWS,
            qkvT + (long)d * 1152 * 384, 384, 0, 1152,
            qkvb, 1152, 0, 0, 1,
            qkv_b + d * 1152, nullptr, 1152, 384);
        k_ropepack<<<(24 * LPAD * 32 + 255) / 256, 256, 0, stream>>>(qkvb, ct, st, Qb, Kb, Vt);
        // fused attention: S -> softmax -> PV, obuf bf16 (B, L, 384)
        k_flash<<<dim3(9, 24), 256, 0, stream>>>(Qb, Kb, Vt, obuf);
        // proj + gamma1 residual into xt
        k_gemm<EPI_RES><<<dim3(MT, Dm / 64, 1), 256, 0, stream>>>(
            obuf, Dm, 0, ROWS,
            projT + (long)d * 384 * 384, 384, 0, 384,
            xt, Dm, 0, 0, 1,
            proj_b + d * Dm, gamma1 + d * Dm, Dm, 384);
        k_ln<true><<<(ROWS + 3) / 4, 256, 0, stream>>>(xt, ln2_g + d * Dm, ln2_b + d * Dm, yb, ROWS);
        // fc1 + gelu -> hid bf16
        k_gemm<EPI_GELU><<<dim3(MT, 1536 / 64, 1), 256, 0, stream>>>(
            yb, Dm, 0, ROWS,
            fc1T + (long)d * 1536 * 384, 384, 0, 1536,
            hid, 1536, 0, 0, 1,
            fc1_b + d * 1536, nullptr, 1536, 384);
        // fc2 + gamma2 residual into xt
        k_gemm<EPI_RES><<<dim3(MT, Dm / 64, 1), 256, 0, stream>>>(
            hid, 1536, 0, ROWS,
            fc2T + (long)d * 384 * 1536, 1536, 0, 384,
            xt, Dm, 0, 0, 1,
            fc2_b + d * Dm, gamma2 + d * Dm, Dm, 1536);
    }
    // final layernorm -> d_out (f32)
    k_ln<false><<<(ROWS + 3) / 4, 256, 0, stream>>>(xt, lnf_g, lnf_b, out, ROWS);
}

// Round 11
// 1291.020 us; speedup vs baseline: 1.5626x; 1.1301x over previous
//
#include <hip/hip_runtime.h>
#include <hip/hip_bf16.h>
#include <math.h>

// ---------------- constants ----------------
#define Bq     4
#define LSEQ   515          // 3 meta + 512 data tokens
#define NMETA  3
#define NPATCH 512
#define Dm     384
#define NHEADS 6
#define HDh    64
#define NDEPTH 12
#define LPAD   544          // 515 padded to multiple of 32
#define KSPL   32           // split-K chunks for meta GEMM
#define KCH    125          // 4000 / KSPL

typedef unsigned short u16;
typedef short bf16x8 __attribute__((ext_vector_type(8)));
typedef float f32x4  __attribute__((ext_vector_type(4)));

enum { EPI_F32 = 0, EPI_BF16 = 1, EPI_GELU = 2, EPI_RES = 3 };

__device__ inline u16 f2bf(float x) {
    __hip_bfloat16 h = __float2bfloat16(x);
    return *reinterpret_cast<u16*>(&h);
}
__device__ inline float bf2f(u16 x) {
    __hip_bfloat16 h = *reinterpret_cast<__hip_bfloat16*>(&x);
    return __bfloat162float(h);
}

// ---------------- weight transpose + cast: W (R x C) f32 -> WT (C x R) bf16, per layer z ----
__global__ __launch_bounds__(256)
void k_transpose(const float* __restrict__ W, u16* __restrict__ WT, int R, int C) {
    __shared__ float tile[32][33];
    int z = blockIdx.z;
    const float* Wz = W + (long)z * R * C;
    u16* Tz = WT + (long)z * R * C;
    int c0 = blockIdx.x * 32, r0 = blockIdx.y * 32;
    int tx = threadIdx.x & 31, ty = threadIdx.x >> 5;     // 32 x 8
    for (int rr = ty; rr < 32; rr += 8)
        tile[rr][tx] = Wz[(long)(r0 + rr) * C + c0 + tx];
    __syncthreads();
    for (int rr = ty; rr < 32; rr += 8)
        Tz[(long)(c0 + rr) * R + r0 + tx] = f2bf(tile[tx][rr]);
}

// ---------------- patch im2col + hi/lo bf16 split: A row m = [xh|xh|xl] (768) ----
__global__ __launch_bounds__(256)
void k_split(const float* __restrict__ x, u16* __restrict__ A) {
    int m = blockIdx.x;               // 0..2047  (b*512 + n)
    int b = m >> 9, n = m & 511;
    int i = n >> 6, j = n & 63;       // patch grid 8 x 64
    int t = threadIdx.x;
    int pr = t >> 4, pc = t & 15;
    float v = x[(long)b * 131072 + (i * 16 + pr) * 1024 + j * 16 + pc];
    u16 hi = f2bf(v);
    u16 lo = f2bf(v - bf2f(hi));
    u16* row = A + (long)m * 768;
    row[t] = hi; row[256 + t] = hi; row[512 + t] = lo;
}

// ---------------- patch weight hi/lo split: Bt row d = [wh|wl|wh] (768) -------
__global__ __launch_bounds__(256)
void k_wsplit(const float* __restrict__ pw, u16* __restrict__ Bt) {
    int idx = blockIdx.x * 256 + threadIdx.x;   // over 384*256
    if (idx >= Dm * 256) return;
    int d = idx >> 8, k = idx & 255;
    float v = pw[idx];
    u16 hi = f2bf(v);
    u16 lo = f2bf(v - bf2f(hi));
    u16* row = Bt + (long)d * 768;
    row[k] = hi; row[256 + k] = lo; row[512 + k] = hi;
}

// ---------------- stable argsort of noise rows (512) via bitonic w/ index tie-break ----
__global__ __launch_bounds__(512)
void k_argsort(const float* __restrict__ noise, int* __restrict__ ids) {
    __shared__ float v[512];
    __shared__ int   ix[512];
    int b = blockIdx.x, t = threadIdx.x;
    v[t] = noise[b * 512 + t]; ix[t] = t;
    __syncthreads();
    for (int k = 2; k <= 512; k <<= 1)
        for (int j = k >> 1; j > 0; j >>= 1) {
            int p = t ^ j;
            if (p > t) {
                bool up = (t & k) == 0;
                float va = v[t], vb = v[p]; int ia = ix[t], ib = ix[p];
                bool sw = (va > vb) || (va == vb && ia > ib);
                if (sw == up) { v[t] = vb; v[p] = va; ix[t] = ib; ix[p] = ia; }
            }
            __syncthreads();
        }
    ids[b * 512 + t] = ix[t];
}

// ---------------- gather data tokens into xt rows [3..514], + pb + chan_table ----
__global__ void k_gather(const float* __restrict__ tmp, const int* __restrict__ ids,
                         const float* __restrict__ pb, const float* __restrict__ ctab,
                         const int* __restrict__ chan, float* __restrict__ xt) {
    long t = (long)blockIdx.x * 256 + threadIdx.x;
    if (t >= (long)Bq * NPATCH * Dm) return;
    int d = t % Dm; long r = t / Dm;
    int j = r % NPATCH, b = r / NPATCH;
    int src = ids[b * NPATCH + j];
    int ch = chan[b * NPATCH + src];
    xt[((long)b * LSEQ + NMETA + j) * Dm + d] =
        tmp[((long)b * NPATCH + src) * Dm + d] + pb[d] + ctab[(long)ch * Dm + d];
}

// ---------------- meta tokens, split-K stage 1: partial[g][c][d] --------------
__global__ __launch_bounds__(192)
void k_meta1(const float* __restrict__ means, const float* __restrict__ stds,
             const float* __restrict__ mw, float* __restrict__ part) {
    int g = blockIdx.x, c = blockIdx.y;
    int d = threadIdx.x;
    int p = g & 1, mi = (g >> 1) & 1, b = g >> 2;
    const float* row = (p ? stds : means) + (long)(b * 2 + mi) * 4000 + c * KCH;
    const float* w = mw + (long)c * KCH * 192 + d;
    float a = 0.f;
    #pragma unroll 5
    for (int k = 0; k < KCH; k++) a += row[k] * w[(long)k * 192];
    part[((long)g * KSPL + c) * 192 + d] = a;
}

// ---------------- meta stage 2: reduce partials + bias -> xt rows 1,2 ---------
__global__ __launch_bounds__(192)
void k_meta2(const float* __restrict__ part, const float* __restrict__ mb,
             float* __restrict__ xt) {
    int g = blockIdx.x, d = threadIdx.x;
    int p = g & 1, mi = (g >> 1) & 1, b = g >> 2;
    float a = mb[d];
    #pragma unroll 8
    for (int c = 0; c < KSPL; c++) a += part[((long)g * KSPL + c) * 192 + d];
    xt[((long)b * LSEQ + 1 + mi) * Dm + p * 192 + d] = a;
}

// ---------------- cls row ----------------------------------------------------
__global__ void k_cls(const float* __restrict__ cls, float* __restrict__ xt) {
    int t = blockIdx.x * 256 + threadIdx.x;
    if (t >= Bq * Dm) return;
    int b = t / Dm, d = t % Dm;
    xt[(long)b * LSEQ * Dm + d] = cls[d];
}

// ---------------- meta_patches / mask / n_meta outputs -----------------------
__global__ void k_outextra(const float* __restrict__ xt, float* __restrict__ out) {
    int t = blockIdx.x * 256 + threadIdx.x;
    const int META = Bq * NMETA * Dm;          // 4608
    const int MASKN = Bq * NPATCH;             // 2048
    if (t < META) {
        int d = t % Dm; int r = t / Dm; int b = r / NMETA, mi = r % NMETA;
        out[791040 + t] = xt[((long)b * LSEQ + mi) * Dm + d];
    } else if (t < META + MASKN) {
        out[791040 + t] = 0.0f;                // mask (len_keep == 512)
    } else if (t == META + MASKN) {
        out[791040 + t] = 3.0f;                // n_meta
    }
}

// ---------------- RoPE cos/sin table -----------------------------------------
__global__ void k_ropetab(const int* __restrict__ win, float* __restrict__ ct,
                          float* __restrict__ st) {
    int t = blockIdx.x * 256 + threadIdx.x;
    if (t >= NPATCH * 32) return;
    int p = t & 31, n = t >> 5;
    int i = n >> 6, j = n & 63;
    float step = (float)(*win) * 0.25f / 0.125f;
    float inv, ang;
    if (p < 16) { inv = powf(100.0f, -(float)p / 16.0f);        ang = (float)j * step * inv; }
    else        { inv = powf(100.0f, -(float)(p - 16) / 16.0f); ang = (float)i * inv; }
    ct[t] = cosf(ang); st[t] = sinf(ang);
}

// ---------------- layernorm: 1 wave per row, D=384 ---------------------------
template<bool OUT_BF16>
__global__ __launch_bounds__(256)
void k_ln(const float* __restrict__ X, const float* __restrict__ g,
          const float* __restrict__ b, void* __restrict__ Y, int nrows) {
    int row = blockIdx.x * 4 + (threadIdx.x >> 6);
    if (row >= nrows) return;
    int lane = threadIdx.x & 63;
    const float* xr = X + (long)row * Dm;
    float v[6], s = 0.f;
    #pragma unroll
    for (int i = 0; i < 6; i++) { v[i] = xr[lane + 64 * i]; s += v[i]; }
    for (int off = 32; off; off >>= 1) s += __shfl_down(s, off);
    s = __shfl(s, 0);
    float mu = s / (float)Dm, vs = 0.f;
    #pragma unroll
    for (int i = 0; i < 6; i++) { float d = v[i] - mu; vs += d * d; }
    for (int off = 32; off; off >>= 1) vs += __shfl_down(vs, off);
    vs = __shfl(vs, 0);
    float rs = rsqrtf(vs / (float)Dm + 1e-6f);
    #pragma unroll
    for (int i = 0; i < 6; i++) {
        int c = lane + 64 * i;
        float o = (v[i] - mu) * rs * g[c] + b[c];
        if (OUT_BF16) ((u16*)Y)[(long)row * Dm + c] = f2bf(o);
        else          ((float*)Y)[(long)row * Dm + c] = o;
    }
}

// ---------------- rope apply + pack q/k/v (bf16 input) ------------------------
// Qb, Kb: (B*H, 544, 64) row = token; Vt: (B*H, 64, 544) transposed
__global__ void k_ropepack(const u16* __restrict__ qkv, const float* __restrict__ ct,
                           const float* __restrict__ st, u16* __restrict__ Qb,
                           u16* __restrict__ Kb, u16* __restrict__ Vt) {
    long tid = (long)blockIdx.x * 256 + threadIdx.x;   // over 24*544*32
    if (tid >= (long)24 * LPAD * 32) return;
    int p = tid & 31;
    long r = tid >> 5;
    int n = r % LPAD; long bh = r / LPAD;
    int b = bh / NHEADS, h = bh % NHEADS;
    float q0 = 0, q1 = 0, k0 = 0, k1 = 0, v0 = 0, v1 = 0;
    if (n < LSEQ) {
        const u16* base = qkv + ((long)(b * LSEQ + n) * 1152 + h * HDh + 2 * p);
        q0 = bf2f(base[0]);   q1 = bf2f(base[1]);
        k0 = bf2f(base[384]); k1 = bf2f(base[385]);
        v0 = bf2f(base[768]); v1 = bf2f(base[769]);
        if (n >= NMETA) {
            int j = n - NMETA;
            float c = ct[j * 32 + p], s = st[j * 32 + p], a;
            a = q0 * c - q1 * s; q1 = q0 * s + q1 * c; q0 = a;
            a = k0 * c - k1 * s; k1 = k0 * s + k1 * c; k0 = a;
        }
    }
    long qo = (bh * LPAD + n) * (long)HDh + 2 * p;
    Qb[qo] = f2bf(q0); Qb[qo + 1] = f2bf(q1);
    Kb[qo] = f2bf(k0); Kb[qo + 1] = f2bf(k1);
    long vo = (bh * (long)HDh + 2 * p) * LPAD + n;
    Vt[vo] = f2bf(v0); Vt[vo + LPAD] = f2bf(v1);
}

// ---------------- fused flash attention ---------------------------------------
// grid (9 q-tiles, 24 bh); 4 waves; wave w owns q rows [q0+16w, q0+16w+16),
// all 64 tokens of the staged K/V tile. Online softmax in registers.
__global__ __launch_bounds__(256)
void k_flash(const u16* __restrict__ Qb, const u16* __restrict__ Kb,
             const u16* __restrict__ Vt, u16* __restrict__ obuf) {
    __shared__ u16 Ql[64][72];
    __shared__ u16 Kl[64][72];
    __shared__ u16 Vl[64][72];       // Vl[d][tok]
    __shared__ u16 Pl[4][16][72];    // wave-private P relayout
    int bh = blockIdx.y;
    int b = bh / NHEADS, h = bh % NHEADS;
    int q0 = blockIdx.x * 64;
    int t = threadIdx.x, lane = t & 63, w = t >> 6;
    int srow = t >> 2, scol = (t & 3) * 16;
    int fr = lane & 15, kq = lane >> 4;
    const uint4 z4 = make_uint4(0, 0, 0, 0);

    // stage Q tile (rows beyond LPAD -> 0; rows 515..543 already 0 in Qb)
    {
        uint4 v0 = z4, v1 = z4;
        if (q0 + srow < LPAD) {
            const u16* p = Qb + ((long)bh * LPAD + q0 + srow) * HDh + scol;
            v0 = *(const uint4*)p; v1 = *(const uint4*)(p + 8);
        }
        *(uint4*)&Ql[srow][scol] = v0;
        *(uint4*)&Ql[srow][scol + 8] = v1;
    }

    float m_r[4], l_r[4];
    #pragma unroll
    for (int r = 0; r < 4; r++) { m_r[r] = -1e30f; l_r[r] = 0.f; }
    f32x4 Of[4] = {};

    for (int kt = 0; kt < 9; kt++) {
        int kv0 = kt * 64;
        // issue global loads for K/V tile
        uint4 kv0r = z4, kv1r = z4, vv0 = z4, vv1 = z4;
        if (kv0 + srow < LPAD) {
            const u16* p = Kb + ((long)bh * LPAD + kv0 + srow) * HDh + scol;
            kv0r = *(const uint4*)p; kv1r = *(const uint4*)(p + 8);
        }
        if (kv0 + scol < LPAD) {     // 16-col chunks: fully valid or fully OOB
            const u16* pv = Vt + ((long)bh * HDh + srow) * LPAD + kv0 + scol;
            vv0 = *(const uint4*)pv; vv1 = *(const uint4*)(pv + 8);
        }
        __syncthreads();             // previous iteration's LDS reads done
        *(uint4*)&Kl[srow][scol] = kv0r;
        *(uint4*)&Kl[srow][scol + 8] = kv1r;
        *(uint4*)&Vl[srow][scol] = vv0;
        *(uint4*)&Vl[srow][scol + 8] = vv1;
        __syncthreads();

        // S = Q K^T for this wave's 16 q rows x 64 tokens
        f32x4 sa[4] = {};
        #pragma unroll
        for (int ks = 0; ks < 2; ks++) {
            bf16x8 af = *(const bf16x8*)&Ql[w * 16 + fr][ks * 32 + kq * 8];
            #pragma unroll
            for (int nj = 0; nj < 4; nj++) {
                bf16x8 bg = *(const bf16x8*)&Kl[nj * 16 + fr][ks * 32 + kq * 8];
                sa[nj] = __builtin_amdgcn_mfma_f32_16x16x32_bf16(af, bg, sa[nj], 0, 0, 0);
            }
        }
        // mask + scale, row max
        float rm[4], rs[4];
        #pragma unroll
        for (int r = 0; r < 4; r++) rm[r] = -1e30f;
        #pragma unroll
        for (int nj = 0; nj < 4; nj++) {
            bool valid = (kv0 + nj * 16 + fr) < LSEQ;
            #pragma unroll
            for (int r = 0; r < 4; r++) {
                float s = valid ? sa[nj][r] * 0.125f : -1e30f;
                sa[nj][r] = s;
                rm[r] = fmaxf(rm[r], s);
            }
        }
        #pragma unroll
        for (int r = 0; r < 4; r++) {
            #pragma unroll
            for (int off = 1; off < 16; off <<= 1)
                rm[r] = fmaxf(rm[r], __shfl_xor(rm[r], off));
        }
        float sc[4];
        #pragma unroll
        for (int r = 0; r < 4; r++) {
            float mn = fmaxf(m_r[r], rm[r]);
            sc[r] = __expf(m_r[r] - mn);
            m_r[r] = mn;
            rs[r] = 0.f;
        }
        #pragma unroll
        for (int nj = 0; nj < 4; nj++)
            #pragma unroll
            for (int r = 0; r < 4; r++) {
                float p = __expf(sa[nj][r] - m_r[r]);   // masked -> 0
                sa[nj][r] = p;
                rs[r] += p;
            }
        #pragma unroll
        for (int r = 0; r < 4; r++) {
            #pragma unroll
            for (int off = 1; off < 16; off <<= 1)
                rs[r] += __shfl_xor(rs[r], off);
            l_r[r] = l_r[r] * sc[r] + rs[r];
        }
        // P: C-layout regs -> wave-private LDS -> A-frag layout
        #pragma unroll
        for (int nj = 0; nj < 4; nj++)
            #pragma unroll
            for (int r = 0; r < 4; r++)
                Pl[w][kq * 4 + r][nj * 16 + fr] = f2bf(sa[nj][r]);
        bf16x8 pa0 = *(const bf16x8*)&Pl[w][fr][kq * 8];
        bf16x8 pa1 = *(const bf16x8*)&Pl[w][fr][32 + kq * 8];
        // rescale O, accumulate P V
        #pragma unroll
        for (int nd = 0; nd < 4; nd++)
            #pragma unroll
            for (int r = 0; r < 4; r++) Of[nd][r] *= sc[r];
        #pragma unroll
        for (int nd = 0; nd < 4; nd++) {
            bf16x8 bg0 = *(const bf16x8*)&Vl[nd * 16 + fr][kq * 8];
            bf16x8 bg1 = *(const bf16x8*)&Vl[nd * 16 + fr][32 + kq * 8];
            Of[nd] = __builtin_amdgcn_mfma_f32_16x16x32_bf16(pa0, bg0, Of[nd], 0, 0, 0);
            Of[nd] = __builtin_amdgcn_mfma_f32_16x16x32_bf16(pa1, bg1, Of[nd], 0, 0, 0);
        }
    }
    // normalize + store
    #pragma unroll
    for (int r = 0; r < 4; r++) {
        int q = q0 + w * 16 + kq * 4 + r;
        if (q >= LSEQ) continue;
        float inv = 1.0f / l_r[r];
        #pragma unroll
        for (int nd = 0; nd < 4; nd++)
            obuf[((long)b * LSEQ + q) * Dm + h * HDh + nd * 16 + fr] = f2bf(Of[nd][r] * inv);
    }
}

// ---------------- generic batched bf16 MFMA GEMM (BK=64, reg-prefetch) --------
// C[m][n] = epi( sum_k A[m][k] * Bt[n][k] + bias[n] );  K must be mult of 64.
template<int EPI>
__global__ __launch_bounds__(256)
void k_gemm(const u16* __restrict__ A, int lda, long sA, int M,
            const u16* __restrict__ Bt, int ldb, long sB, int btRows,
            void* __restrict__ Cptr, int ldc, long sCz1, long sCz2, int hdiv,
            const float* __restrict__ bias, const float* __restrict__ gamma,
            int N, int K) {
    __shared__ u16 Al[64][72];
    __shared__ u16 Bl[64][72];
    int z = blockIdx.z;
    const u16* Ab = A + (long)z * sA;
    const u16* Bb = Bt + (long)z * sB;
    long coff = (long)(z / hdiv) * sCz1 + (long)(z % hdiv) * sCz2;
    int row0 = blockIdx.x * 64, col0 = blockIdx.y * 64;
    int t = threadIdx.x;
    int lane = t & 63, w = t >> 6;
    int wr = (w >> 1) * 32, wc = (w & 1) * 32;
    int srow = t >> 2, sk = (t & 3) * 16;       // 4 threads/row, 16 elem (32B) each
    const uint4 z4 = make_uint4(0, 0, 0, 0);
    bool aok = (row0 + srow < M), bok = (col0 + srow < btRows);
    f32x4 acc[2][2] = {};
    uint4 av0, av1, bv0, bv1;
    auto issue = [&](int kk) {
        av0 = av1 = bv0 = bv1 = z4;
        if (aok) {
            const u16* p = Ab + (long)(row0 + srow) * lda + kk + sk;
            av0 = *(const uint4*)p; av1 = *(const uint4*)(p + 8);
        }
        if (bok) {
            const u16* p = Bb + (long)(col0 + srow) * ldb + kk + sk;
            bv0 = *(const uint4*)p; bv1 = *(const uint4*)(p + 8);
        }
    };
    issue(0);
    int fr = lane & 15, kg = (lane >> 4) * 8;
    for (int kk = 0; kk < K; kk += 64) {
        __syncthreads();                          // prior reads done
        *(uint4*)(&Al[srow][sk]) = av0; *(uint4*)(&Al[srow][sk + 8]) = av1;
        *(uint4*)(&Bl[srow][sk]) = bv0; *(uint4*)(&Bl[srow][sk + 8]) = bv1;
        __syncthreads();
        if (kk + 64 < K) issue(kk + 64);          // prefetch next tile into regs
        #pragma unroll
        for (int ks = 0; ks < 2; ks++) {
            bf16x8 af[2], bg[2];
            #pragma unroll
            for (int i = 0; i < 2; i++) {
                af[i] = *(const bf16x8*)(&Al[wr + 16 * i + fr][ks * 32 + kg]);
                bg[i] = *(const bf16x8*)(&Bl[wc + 16 * i + fr][ks * 32 + kg]);
            }
            #pragma unroll
            for (int mi = 0; mi < 2; mi++)
                #pragma unroll
                for (int nj = 0; nj < 2; nj++)
                    acc[mi][nj] = __builtin_amdgcn_mfma_f32_16x16x32_bf16(af[mi], bg[nj], acc[mi][nj], 0, 0, 0);
        }
    }
    int rg = (lane >> 4) * 4;
    #pragma unroll
    for (int mi = 0; mi < 2; mi++)
        #pragma unroll
        for (int nj = 0; nj < 2; nj++)
            #pragma unroll
            for (int r = 0; r < 4; r++) {
                int row = row0 + wr + 16 * mi + rg + r;
                int col = col0 + wc + 16 * nj + fr;
                if (row >= M || col >= N) continue;
                float v = acc[mi][nj][r];
                if (bias) v += bias[col];
                long idx = coff + (long)row * ldc + col;
                if (EPI == EPI_F32)      ((float*)Cptr)[idx] = v;
                else if (EPI == EPI_BF16)((u16*)Cptr)[idx] = f2bf(v);
                else if (EPI == EPI_GELU) {
                    v = 0.5f * v * (1.0f + erff(v * 0.70710678118f));
                    ((u16*)Cptr)[idx] = f2bf(v);
                } else { // EPI_RES (in-place residual on f32 C)
                    float* C = (float*)Cptr;
                    C[idx] = C[idx] + gamma[col] * v;
                }
            }
}

// ---------------- host orchestration -----------------------------------------
extern "C" void kernel_launch(void* const* d_in, const int* in_sizes, int n_in,
                              void* d_out, int out_size, void* d_ws, size_t ws_size,
                              hipStream_t stream) {
    const float* x        = (const float*)d_in[0];
    const float* means    = (const float*)d_in[1];
    const float* stds     = (const float*)d_in[2];
    const int*   channels = (const int*)  d_in[3];
    const float* noise    = (const float*)d_in[4];
    const int*   win_size = (const int*)  d_in[5];
    // d_in[6] = mask_ratio (0)
    const float* patch_w  = (const float*)d_in[7];
    const float* patch_b  = (const float*)d_in[8];
    const float* cls_tok  = (const float*)d_in[9];
    const float* chan_tab = (const float*)d_in[10];
    const float* mean_w   = (const float*)d_in[11];
    const float* mean_b   = (const float*)d_in[12];
    const float* qkv_w    = (const float*)d_in[13];
    const float* qkv_b    = (const float*)d_in[14];
    const float* proj_w   = (const float*)d_in[15];
    const float* proj_b   = (const float*)d_in[16];
    const float* fc1_w    = (const float*)d_in[17];
    const float* fc1_b    = (const float*)d_in[18];
    const float* fc2_w    = (const float*)d_in[19];
    const float* fc2_b    = (const float*)d_in[20];
    const float* ln1_g    = (const float*)d_in[21];
    const float* ln1_b    = (const float*)d_in[22];
    const float* ln2_g    = (const float*)d_in[23];
    const float* ln2_b    = (const float*)d_in[24];
    const float* gamma1   = (const float*)d_in[25];
    const float* gamma2   = (const float*)d_in[26];
    const float* lnf_g    = (const float*)d_in[27];
    const float* lnf_b    = (const float*)d_in[28];
    float* out = (float*)d_out;

    char* wp = (char*)d_ws;
    auto alloc = [&](size_t bytes) { char* p = wp; wp += (bytes + 255) & ~(size_t)255; return p; };
    u16*   qkvT  = (u16*)  alloc((size_t)NDEPTH * 1152 * 384 * 2);
    u16*   projT = (u16*)  alloc((size_t)NDEPTH * 384 * 384 * 2);
    u16*   fc1T  = (u16*)  alloc((size_t)NDEPTH * 1536 * 384 * 2);
    u16*   fc2T  = (u16*)  alloc((size_t)NDEPTH * 384 * 1536 * 2);
    float* xt    = (float*)alloc((size_t)Bq * LSEQ * Dm * 4);
    u16*   yb    = (u16*)  alloc((size_t)Bq * LSEQ * Dm * 2);
    u16*   qkvb  = (u16*)  alloc((size_t)Bq * LSEQ * 1152 * 2);
    u16*   Qb    = (u16*)  alloc((size_t)24 * LPAD * HDh * 2);
    u16*   Kb    = (u16*)  alloc((size_t)24 * LPAD * HDh * 2);
    u16*   Vt    = (u16*)  alloc((size_t)24 * HDh * LPAD * 2);
    u16*   obuf  = (u16*)  alloc((size_t)Bq * LSEQ * Dm * 2);
    u16*   hid   = (u16*)  alloc((size_t)Bq * LSEQ * 1536 * 2);
    float* tmp   = (float*)alloc((size_t)Bq * NPATCH * Dm * 4);
    float* ct    = (float*)alloc((size_t)NPATCH * 32 * 4);
    float* st    = (float*)alloc((size_t)NPATCH * 32 * 4);
    int*   ids   = (int*)  alloc((size_t)Bq * NPATCH * 4);
    float* mpart = (float*)alloc((size_t)16 * KSPL * 192 * 4);
    u16*   Axl   = (u16*)  alloc((size_t)Bq * NPATCH * 768 * 2);
    u16*   Bw    = (u16*)  alloc((size_t)Dm * 768 * 2);

    // weights -> bf16 transposed
    k_transpose<<<dim3(1152 / 32, 384 / 32, NDEPTH), 256, 0, stream>>>(qkv_w, qkvT, 384, 1152);
    k_transpose<<<dim3(384 / 32, 384 / 32, NDEPTH), 256, 0, stream>>>(proj_w, projT, 384, 384);
    k_transpose<<<dim3(1536 / 32, 384 / 32, NDEPTH), 256, 0, stream>>>(fc1_w, fc1T, 384, 1536);
    k_transpose<<<dim3(384 / 32, 1536 / 32, NDEPTH), 256, 0, stream>>>(fc2_w, fc2T, 1536, 384);

    // patch embed as hi/lo bf16 MFMA GEMM: tmp[m][d] = patch(m) . pw(d)
    k_split<<<Bq * NPATCH, 256, 0, stream>>>(x, Axl);
    k_wsplit<<<(Dm * 256 + 255) / 256, 256, 0, stream>>>(patch_w, Bw);
    k_gemm<EPI_F32><<<dim3(Bq * NPATCH / 64, Dm / 64, 1), 256, 0, stream>>>(
        Axl, 768, 0, Bq * NPATCH,
        Bw, 768, 0, Dm,
        tmp, Dm, 0, 0, 1,
        nullptr, nullptr, Dm, 768);

    // build initial xt
    k_argsort<<<Bq, 512, 0, stream>>>(noise, ids);
    k_gather<<<(Bq * NPATCH * Dm + 255) / 256, 256, 0, stream>>>(tmp, ids, patch_b, chan_tab, channels, xt);
    k_meta1<<<dim3(16, KSPL), 192, 0, stream>>>(means, stds, mean_w, mpart);
    k_meta2<<<16, 192, 0, stream>>>(mpart, mean_b, xt);
    k_cls<<<(Bq * Dm + 255) / 256, 256, 0, stream>>>(cls_tok, xt);
    k_outextra<<<(4608 + 2048 + 1 + 255) / 256, 256, 0, stream>>>(xt, out);
    k_ropetab<<<(NPATCH * 32 + 255) / 256, 256, 0, stream>>>(win_size, ct, st);

    const int ROWS = Bq * LSEQ;        // 2060
    const int MT = (ROWS + 63) / 64;   // 33
    for (int d = 0; d < NDEPTH; d++) {
        k_ln<true><<<(ROWS + 3) / 4, 256, 0, stream>>>(xt, ln1_g + d * Dm, ln1_b + d * Dm, yb, ROWS);
        // qkv: (2060 x 384) @ (384 x 1152) + b -> bf16
        k_gemm<EPI_BF16><<<dim3(MT, 1152 / 64, 1), 256, 0, stream>>>(
            yb, Dm, 0, ROWS,
            qkvT + (long)d * 1152 * 384, 384, 0, 1152,
            qkvb, 1152, 0, 0, 1,
            qkv_b + d * 1152, nullptr, 1152, 384);
        k_ropepack<<<(24 * LPAD * 32 + 255) / 256, 256, 0, stream>>>(qkvb, ct, st, Qb, Kb, Vt);
        // fused attention: S -> softmax -> PV, obuf bf16 (B, L, 384)
        k_flash<<<dim3(9, 24), 256, 0, stream>>>(Qb, Kb, Vt, obuf);
        // proj + gamma1 residual into xt
        k_gemm<EPI_RES><<<dim3(MT, Dm / 64, 1), 256, 0, stream>>>(
            obuf, Dm, 0, ROWS,
            projT + (long)d * 384 * 384, 384, 0, 384,
            xt, Dm, 0, 0, 1,
            proj_b + d * Dm, gamma1 + d * Dm, Dm, 384);
        k_ln<true><<<(ROWS + 3) / 4, 256, 0, stream>>>(xt, ln2_g + d * Dm, ln2_b + d * Dm, yb, ROWS);
        // fc1 + gelu -> hid bf16
        k_gemm<EPI_GELU><<<dim3(MT, 1536 / 64, 1), 256, 0, stream>>>(
            yb, Dm, 0, ROWS,
            fc1T + (long)d * 1536 * 384, 384, 0, 1536,
            hid, 1536, 0, 0, 1,
            fc1_b + d * 1536, nullptr, 1536, 384);
        // fc2 + gamma2 residual into xt
        k_gemm<EPI_RES><<<dim3(MT, Dm / 64, 1), 256, 0, stream>>>(
            hid, 1536, 0, ROWS,
            fc2T + (long)d * 384 * 1536, 1536, 0, 384,
            xt, Dm, 0, 0, 1,
            fc2_b + d * Dm, gamma2 + d * Dm, Dm, 1536);
    }
    // final layernorm -> d_out (f32)
    k_ln<false><<<(ROWS + 3) / 4, 256, 0, stream>>>(xt, lnf_g, lnf_b, out, ROWS);
}